// Round 2
// baseline (414.190 us; speedup 1.0000x reference)
//
#include <hip/hip_runtime.h>
#include <hip/hip_bf16.h>

#define BB 8
#define SS 2048
#define DD 256
#define CC 32
#define HH 4
#define HD 64
#define MTOT (BB*SS)   // 16384 tokens

using bf16    = __hip_bfloat16;
using short8  = __attribute__((ext_vector_type(8))) short;
using floatx4 = __attribute__((ext_vector_type(4))) float;

__device__ inline float bf2f(unsigned short u) {
    union { unsigned int i; float f; } v; v.i = ((unsigned int)u) << 16; return v.f;
}
__device__ inline unsigned short f2bfbits(float f) {
    bf16 h = __float2bfloat16(f);
    return __builtin_bit_cast(unsigned short, h);
}

// --------------------------------------------------------------------------
// Input element counts (compile-time, from reference shapes), prefix sums.
// --------------------------------------------------------------------------
#define N_X    (MTOT*DD)     // 4194304
#define N_COND (MTOT*CC)     // 524288
#define N_WQW  (DD*DD)       // 65536
#define N_WQB  (DD)          // 256
#define N_WVW  (DD*DD)
#define N_WVB  (DD)
#define N_WKW  (CC*DD*DD)    // 2097152
#define N_WKB  (CC*DD)       // 8192
#define N_WOW  (DD*DD)
#define N_WOB  (DD)
#define P0 0
#define P1 (P0+N_X)
#define P2 (P1+N_COND)
#define P3 (P2+N_WQW)
#define P4 (P3+N_WQB)
#define P5 (P4+N_WVW)
#define P6 (P5+N_WVB)
#define P7 (P6+N_WKW)
#define P8 (P7+N_WKB)
#define P9 (P8+N_WOW)
#define PTOT (P9+N_WOB)      // 7021312

// --------------------------------------------------------------------------
// Dtype detector: sample x's first 4096 words as fp32. True fp32 N(0,1):
// ~all |v| in [1e-4,1e4]. bf16-pairs-as-fp32: exponent field is random-ish
// shifted bf16 bits -> magnitudes ~2^-68 / 2^60, count ~0.
// flag=1 -> inputs are fp32; flag=0 -> inputs are bf16.
// --------------------------------------------------------------------------
__global__ void detect_dtype(const void* x, int* flag)
{
    __shared__ int total;
    if (threadIdx.x == 0) total = 0;
    __syncthreads();
    const float* xf = (const float*)x;
    int cnt = 0;
    for (int i = threadIdx.x; i < 4096; i += 256) {
        float v = fabsf(xf[i]);
        if (v == v && v > 1e-4f && v < 1e4f) cnt++;
    }
    atomicAdd(&total, cnt);
    __syncthreads();
    if (threadIdx.x == 0) *flag = (total > 2048) ? 1 : 0;
}

// --------------------------------------------------------------------------
// Fused conversion of all 10 inputs into one contiguous bf16 region.
// --------------------------------------------------------------------------
__global__ void convert_all(const void* s0, const void* s1, const void* s2,
                            const void* s3, const void* s4, const void* s5,
                            const void* s6, const void* s7, const void* s8,
                            const void* s9, bf16* dst, const int* flagp)
{
    const bool f32 = (*flagp != 0);
    size_t i = ((size_t)blockIdx.x * 256 + threadIdx.x) * 8;
    const size_t stride = (size_t)gridDim.x * 256 * 8;
    for (; i < (size_t)PTOT; i += stride) {
        const void* src; size_t off;
        if      (i < P1) { src = s0; off = i - P0; }
        else if (i < P2) { src = s1; off = i - P1; }
        else if (i < P3) { src = s2; off = i - P2; }
        else if (i < P4) { src = s3; off = i - P3; }
        else if (i < P5) { src = s4; off = i - P4; }
        else if (i < P6) { src = s5; off = i - P5; }
        else if (i < P7) { src = s6; off = i - P6; }
        else if (i < P8) { src = s7; off = i - P7; }
        else if (i < P9) { src = s8; off = i - P8; }
        else             { src = s9; off = i - P9; }
        if (f32) {
            const float* s = (const float*)src + off;
            float4 a = *(const float4*)(s);
            float4 b = *(const float4*)(s + 4);
            __align__(16) unsigned short t[8];
            t[0] = f2bfbits(a.x); t[1] = f2bfbits(a.y);
            t[2] = f2bfbits(a.z); t[3] = f2bfbits(a.w);
            t[4] = f2bfbits(b.x); t[5] = f2bfbits(b.y);
            t[6] = f2bfbits(b.z); t[7] = f2bfbits(b.w);
            *(uint4*)(dst + i) = *(const uint4*)t;
        } else {
            *(uint4*)(dst + i) = *(const uint4*)((const unsigned short*)src + off);
        }
    }
}

// ---------------------------------------------------------------------------
// GEMM: Y[m,n] = sum_k X[m,k] * W[n,k] + bias[n]   (torch Linear, M x 256 x 256)
// grid (N/64, M/64), block 256 (4 waves); 64x64 tile, whole K=256 staged once.
// flex_out: 0 -> write bf16 always; 1 -> fp32 if *flagp else bf16.
// ---------------------------------------------------------------------------
__launch_bounds__(256, 2)
__global__ void gemm_bias(const bf16* __restrict__ X, const bf16* __restrict__ W,
                          const bf16* __restrict__ bias, void* __restrict__ Yv,
                          const int* __restrict__ flagp, int flex_out)
{
    const int LDT = 264;                       // row stride (shorts), +8 pad
    __shared__ __align__(16) unsigned short xs[64 * 264];
    __shared__ __align__(16) unsigned short ws[64 * 264];
    const int t  = threadIdx.x;
    const int m0 = blockIdx.y * 64;
    const int n0 = blockIdx.x * 64;

    for (int i = 0; i < 8; ++i) {              // 2048 x 16B chunks per tile
        int c = t + i * 256;
        int row = c >> 5, col = (c & 31) * 8;
        *(uint4*)&xs[row * LDT + col] = *(const uint4*)(X + (size_t)(m0 + row) * DD + col);
        *(uint4*)&ws[row * LDT + col] = *(const uint4*)(W + (size_t)(n0 + row) * DD + col);
    }
    __syncthreads();

    const int w = t >> 6, lane = t & 63;
    const int lrow = lane & 15, lk = (lane >> 4) * 8, rgrp = (lane >> 4) * 4;
    floatx4 acc[4] = {};
    const unsigned short* ax = &xs[(w * 16 + lrow) * LDT + lk];
    for (int kt = 0; kt < 8; ++kt) {
        short8 a = *(const short8*)(ax + kt * 32);
        #pragma unroll
        for (int j = 0; j < 4; ++j) {
            short8 b = *(const short8*)&ws[(j * 16 + lrow) * LDT + kt * 32 + lk];
            acc[j] = __builtin_amdgcn_mfma_f32_16x16x32_bf16(a, b, acc[j], 0, 0, 0);
        }
    }
    const bool f32o = flex_out && (*flagp != 0);
    #pragma unroll
    for (int j = 0; j < 4; ++j) {
        int col = n0 + j * 16 + lrow;
        float bv = __bfloat162float(bias[col]);
        #pragma unroll
        for (int r = 0; r < 4; ++r) {
            int row = m0 + w * 16 + rgrp + r;
            float val = acc[j][r] + bv;
            if (f32o) ((float*)Yv)[(size_t)row * DD + col] = val;
            else      ((bf16*)Yv)[(size_t)row * DD + col] = __float2bfloat16(val);
        }
    }
}

// ---------------------------------------------------------------------------
// Class-dependent key: K[m,f] = sum_c cond[m,c]*((x[m,:] . Wk[c,f,:]) + Wkb[c,f])
// grid (4, 256), block 256. Loops classes; P = X@Wk[c]^T via MFMA, scaled by
// cond per row (C-layout row = (lane>>4)*4+r).
// ---------------------------------------------------------------------------
__launch_bounds__(256, 2)
__global__ void classkey(const bf16* __restrict__ X, const bf16* __restrict__ Cond,
                         const bf16* __restrict__ Wk, const bf16* __restrict__ Wkb,
                         bf16* __restrict__ Kout)
{
    const int LDT = 264;
    __shared__ __align__(16) unsigned short xs[64 * 264];
    __shared__ __align__(16) unsigned short ws[64 * 264];
    __shared__ __align__(16) unsigned short conds[64 * 32];  // [row][c]
    __shared__ __align__(16) unsigned short kbs[32 * 64];    // [c][col]
    const int t  = threadIdx.x;
    const int m0 = blockIdx.y * 64;
    const int n0 = blockIdx.x * 64;

    for (int i = 0; i < 8; ++i) {
        int c = t + i * 256;
        int row = c >> 5, col = (c & 31) * 8;
        *(uint4*)&xs[row * LDT + col] = *(const uint4*)(X + (size_t)(m0 + row) * DD + col);
    }
    {   // cond tile 64x32
        int row = t >> 2, c8 = (t & 3) * 8;
        *(uint4*)&conds[row * 32 + c8] = *(const uint4*)(Cond + (size_t)(m0 + row) * CC + c8);
    }
    {   // Wk_b slice 32x64
        int row = t >> 3, c8 = (t & 7) * 8;
        *(uint4*)&kbs[row * 64 + c8] = *(const uint4*)(Wkb + (size_t)row * DD + n0 + c8);
    }

    const int w = t >> 6, lane = t & 63;
    const int lrow = lane & 15, lk = (lane >> 4) * 8, rgrp = (lane >> 4) * 4;
    floatx4 acck[4] = {};

    for (int c = 0; c < CC; ++c) {
        __syncthreads();                        // prior reads of ws done
        const bf16* Wc = Wk + (size_t)c * DD * DD;
        for (int i = 0; i < 8; ++i) {
            int ch = t + i * 256;
            int row = ch >> 5, col = (ch & 31) * 8;
            *(uint4*)&ws[row * LDT + col] = *(const uint4*)(Wc + (size_t)(n0 + row) * DD + col);
        }
        __syncthreads();

        floatx4 p[4] = {};
        const unsigned short* ax = &xs[(w * 16 + lrow) * LDT + lk];
        for (int kt = 0; kt < 8; ++kt) {
            short8 a = *(const short8*)(ax + kt * 32);
            #pragma unroll
            for (int j = 0; j < 4; ++j) {
                short8 b = *(const short8*)&ws[(j * 16 + lrow) * LDT + kt * 32 + lk];
                p[j] = __builtin_amdgcn_mfma_f32_16x16x32_bf16(a, b, p[j], 0, 0, 0);
            }
        }
        #pragma unroll
        for (int r = 0; r < 4; ++r) {
            float cv = bf2f(conds[(w * 16 + rgrp + r) * 32 + c]);
            #pragma unroll
            for (int j = 0; j < 4; ++j) acck[j][r] += cv * p[j][r];
        }
    }

    // bias: kb[row,col] = sum_c cond[row,c] * Wkb[c,col]
    float kbv[4][4] = {};
    for (int c = 0; c < CC; ++c) {
        #pragma unroll
        for (int r = 0; r < 4; ++r) {
            float cf = bf2f(conds[(w * 16 + rgrp + r) * 32 + c]);
            #pragma unroll
            for (int j = 0; j < 4; ++j)
                kbv[j][r] += cf * bf2f(kbs[c * 64 + j * 16 + lrow]);
        }
    }
    #pragma unroll
    for (int j = 0; j < 4; ++j) {
        int col = n0 + j * 16 + lrow;
        #pragma unroll
        for (int r = 0; r < 4; ++r) {
            int row = m0 + w * 16 + rgrp + r;
            Kout[(size_t)row * DD + col] = __float2bfloat16(acck[j][r] + kbv[j][r]);
        }
    }
}

// ---------------------------------------------------------------------------
// Flash attention per (b,h): Q-tile 64 rows, KV tiles of 64, online softmax.
// Q/K/V read from [16384,256] buffers at column offset h*64 (contiguous 64).
// grid (S/64, B*H), block 256.
// ---------------------------------------------------------------------------
__launch_bounds__(256, 4)
__global__ void attn(const bf16* __restrict__ Q, const bf16* __restrict__ Kb,
                     const bf16* __restrict__ V, bf16* __restrict__ O)
{
    const int LDA = 72;
    __shared__ __align__(16) unsigned short qs[64 * 72];
    __shared__ __align__(16) unsigned short ks[64 * 72];
    __shared__ __align__(16) unsigned short vt[64 * 72];  // transposed: [hd][key]
    __shared__ __align__(16) unsigned short ps[64 * 72];  // wave-private row blocks
    const int t  = threadIdx.x;
    const int bh = blockIdx.y;
    const int b  = bh >> 2, h = bh & 3;
    const int q0 = blockIdx.x * 64;
    const size_t base = ((size_t)b * SS) * DD + h * HD;

    for (int i = 0; i < 2; ++i) {              // Q tile 64x64
        int c = t + i * 256;
        int row = c >> 3, col = (c & 7) * 8;
        *(uint4*)&qs[row * LDA + col] = *(const uint4*)(Q + base + (size_t)(q0 + row) * DD + col);
    }

    const int w = t >> 6, lane = t & 63;
    const int lrow = lane & 15, lk = (lane >> 4) * 8, rgrp = (lane >> 4) * 4;
    floatx4 acco[4] = {};
    float mrun[4] = {-1e30f, -1e30f, -1e30f, -1e30f};
    float lrun[4] = {0.f, 0.f, 0.f, 0.f};

    for (int kt = 0; kt < SS / 64; ++kt) {
        __syncthreads();                        // prior PV reads done
        int k0 = kt * 64;
        for (int i = 0; i < 2; ++i) {
            int c = t + i * 256;
            int row = c >> 3, col = (c & 7) * 8;
            *(uint4*)&ks[row * LDA + col] = *(const uint4*)(Kb + base + (size_t)(k0 + row) * DD + col);
            uint4 vv = *(const uint4*)(V + base + (size_t)(k0 + row) * DD + col);
            __align__(16) unsigned short tmp[8];
            *(uint4*)tmp = vv;
            #pragma unroll
            for (int e = 0; e < 8; ++e) vt[(col + e) * LDA + row] = tmp[e];
        }
        __syncthreads();

        // S = Q @ K^T
        floatx4 s[4] = {};
        #pragma unroll
        for (int k2 = 0; k2 < 2; ++k2) {
            short8 a = *(const short8*)&qs[(w * 16 + lrow) * LDA + k2 * 32 + lk];
            #pragma unroll
            for (int j = 0; j < 4; ++j) {
                short8 bb = *(const short8*)&ks[(j * 16 + lrow) * LDA + k2 * 32 + lk];
                s[j] = __builtin_amdgcn_mfma_f32_16x16x32_bf16(a, bb, s[j], 0, 0, 0);
            }
        }
        #pragma unroll
        for (int j = 0; j < 4; ++j)
            #pragma unroll
            for (int r = 0; r < 4; ++r) s[j][r] *= 0.125f;   // 1/sqrt(64)

        // online softmax (row = (lane>>4)*4+r lives in a 16-lane cluster)
        #pragma unroll
        for (int r = 0; r < 4; ++r) {
            float mx = fmaxf(fmaxf(s[0][r], s[1][r]), fmaxf(s[2][r], s[3][r]));
            #pragma unroll
            for (int d = 1; d < 16; d <<= 1) mx = fmaxf(mx, __shfl_xor(mx, d, 64));
            float mnew = fmaxf(mrun[r], mx);
            float alpha = __expf(mrun[r] - mnew);
            float sum = 0.f;
            #pragma unroll
            for (int j = 0; j < 4; ++j) {
                float e0 = __expf(s[j][r] - mnew);
                s[j][r] = e0;
                sum += e0;
            }
            #pragma unroll
            for (int d = 1; d < 16; d <<= 1) sum += __shfl_xor(sum, d, 64);
            lrun[r] = lrun[r] * alpha + sum;
            mrun[r] = mnew;
            #pragma unroll
            for (int j = 0; j < 4; ++j) acco[j][r] *= alpha;
        }

        // P -> LDS (rows w*16..w*16+15 are written & read only by wave w)
        #pragma unroll
        for (int j = 0; j < 4; ++j)
            #pragma unroll
            for (int r = 0; r < 4; ++r)
                ps[(w * 16 + rgrp + r) * LDA + j * 16 + lrow] = f2bfbits(s[j][r]);

        // O += P @ V
        #pragma unroll
        for (int k2 = 0; k2 < 2; ++k2) {
            short8 a = *(const short8*)&ps[(w * 16 + lrow) * LDA + k2 * 32 + lk];
            #pragma unroll
            for (int j = 0; j < 4; ++j) {
                short8 bb = *(const short8*)&vt[(j * 16 + lrow) * LDA + k2 * 32 + lk];
                acco[j] = __builtin_amdgcn_mfma_f32_16x16x32_bf16(a, bb, acco[j], 0, 0, 0);
            }
        }
    }

    #pragma unroll
    for (int j = 0; j < 4; ++j)
        #pragma unroll
        for (int r = 0; r < 4; ++r) {
            int row = q0 + w * 16 + rgrp + r;
            O[base + (size_t)row * DD + j * 16 + lrow] = __float2bfloat16(acco[j][r] / lrun[r]);
        }
}

// ---------------------------------------------------------------------------
extern "C" void kernel_launch(void* const* d_in, const int* in_sizes, int n_in,
                              void* d_out, int out_size, void* d_ws, size_t ws_size,
                              hipStream_t stream)
{
    int*  flag = (int*)d_ws;
    bf16* conv = (bf16*)((char*)d_ws + 256);

    const bf16* xb    = conv + P0;
    const bf16* condb = conv + P1;
    const bf16* wqw   = conv + P2;
    const bf16* wqb   = conv + P3;
    const bf16* wvw   = conv + P4;
    const bf16* wvb   = conv + P5;
    const bf16* wkw   = conv + P6;
    const bf16* wkb   = conv + P7;
    const bf16* wow   = conv + P8;
    const bf16* wob   = conv + P9;

    bf16* qb = conv + PTOT;
    bf16* kb = qb + (size_t)MTOT * DD;
    bf16* vb = kb + (size_t)MTOT * DD;
    bf16* ob = vb + (size_t)MTOT * DD;

    dim3 blk(256);
    hipLaunchKernelGGL(detect_dtype, dim3(1), blk, 0, stream, d_in[0], flag);
    hipLaunchKernelGGL(convert_all, dim3((PTOT / 8 + 255) / 256), blk, 0, stream,
                       d_in[0], d_in[1], d_in[2], d_in[3], d_in[4],
                       d_in[5], d_in[6], d_in[7], d_in[8], d_in[9],
                       conv, flag);

    dim3 gg(DD / 64, MTOT / 64);               // (4, 256)
    hipLaunchKernelGGL(gemm_bias, gg, blk, 0, stream, xb, wqw, wqb, (void*)qb, flag, 0);
    hipLaunchKernelGGL(gemm_bias, gg, blk, 0, stream, xb, wvw, wvb, (void*)vb, flag, 0);
    hipLaunchKernelGGL(classkey,  gg, blk, 0, stream, xb, condb, wkw, wkb, kb);
    dim3 ga(SS / 64, BB * HH);                 // (32, 32)
    hipLaunchKernelGGL(attn, ga, blk, 0, stream, qb, kb, vb, ob);
    hipLaunchKernelGGL(gemm_bias, gg, blk, 0, stream, ob, wow, wob, d_out, flag, 1);
}

// Round 3
// 339.495 us; speedup vs baseline: 1.2200x; 1.2200x over previous
//
#include <hip/hip_runtime.h>
#include <hip/hip_bf16.h>

#define BB 8
#define SS 2048
#define DD 256
#define CC 32
#define HH 4
#define HD 64
#define MTOT (BB*SS)   // 16384 tokens

using bf16    = __hip_bfloat16;
using short8  = __attribute__((ext_vector_type(8))) short;
using short4v = __attribute__((ext_vector_type(4))) short;
using floatx4 = __attribute__((ext_vector_type(4))) float;

// PV via K=16 MFMA keeps exp'd P entirely in registers (A-layout match).
#if __has_builtin(__builtin_amdgcn_mfma_f32_16x16x16_bf16)
  #define MFMA_PV16(a,b,c) __builtin_amdgcn_mfma_f32_16x16x16_bf16(a,b,c,0,0,0)
  #define HAVE_PV16 1
#elif __has_builtin(__builtin_amdgcn_mfma_f32_16x16x16bf16_1k)
  #define MFMA_PV16(a,b,c) __builtin_amdgcn_mfma_f32_16x16x16bf16_1k(a,b,c,0,0,0)
  #define HAVE_PV16 1
#else
  #define HAVE_PV16 0
#endif

__device__ inline float bf2f(unsigned short u) {
    union { unsigned int i; float f; } v; v.i = ((unsigned int)u) << 16; return v.f;
}
__device__ inline unsigned short f2bfbits(float f) {
    bf16 h = __float2bfloat16(f);
    return __builtin_bit_cast(unsigned short, h);
}

// --------------------------------------------------------------------------
#define N_X    (MTOT*DD)
#define N_COND (MTOT*CC)
#define N_WQW  (DD*DD)
#define N_WQB  (DD)
#define N_WVW  (DD*DD)
#define N_WVB  (DD)
#define N_WKW  (CC*DD*DD)
#define N_WKB  (CC*DD)
#define N_WOW  (DD*DD)
#define N_WOB  (DD)
#define P0 0
#define P1 (P0+N_X)
#define P2 (P1+N_COND)
#define P3 (P2+N_WQW)
#define P4 (P3+N_WQB)
#define P5 (P4+N_WVW)
#define P6 (P5+N_WVB)
#define P7 (P6+N_WKW)
#define P8 (P7+N_WKB)
#define P9 (P8+N_WOW)
#define PTOT (P9+N_WOB)

// --------------------------------------------------------------------------
__global__ void detect_dtype(const void* x, int* flag)
{
    __shared__ int total;
    if (threadIdx.x == 0) total = 0;
    __syncthreads();
    const float* xf = (const float*)x;
    int cnt = 0;
    for (int i = threadIdx.x; i < 4096; i += 256) {
        float v = fabsf(xf[i]);
        if (v == v && v > 1e-4f && v < 1e4f) cnt++;
    }
    atomicAdd(&total, cnt);
    __syncthreads();
    if (threadIdx.x == 0) *flag = (total > 2048) ? 1 : 0;
}

__global__ void convert_all(const void* s0, const void* s1, const void* s2,
                            const void* s3, const void* s4, const void* s5,
                            const void* s6, const void* s7, const void* s8,
                            const void* s9, bf16* dst, const int* flagp)
{
    const bool f32 = (*flagp != 0);
    size_t i = ((size_t)blockIdx.x * 256 + threadIdx.x) * 8;
    const size_t stride = (size_t)gridDim.x * 256 * 8;
    for (; i < (size_t)PTOT; i += stride) {
        const void* src; size_t off;
        if      (i < P1) { src = s0; off = i - P0; }
        else if (i < P2) { src = s1; off = i - P1; }
        else if (i < P3) { src = s2; off = i - P2; }
        else if (i < P4) { src = s3; off = i - P3; }
        else if (i < P5) { src = s4; off = i - P4; }
        else if (i < P6) { src = s5; off = i - P5; }
        else if (i < P7) { src = s6; off = i - P6; }
        else if (i < P8) { src = s7; off = i - P7; }
        else if (i < P9) { src = s8; off = i - P8; }
        else             { src = s9; off = i - P9; }
        if (f32) {
            const float* s = (const float*)src + off;
            float4 a = *(const float4*)(s);
            float4 b = *(const float4*)(s + 4);
            __align__(16) unsigned short t[8];
            t[0] = f2bfbits(a.x); t[1] = f2bfbits(a.y);
            t[2] = f2bfbits(a.z); t[3] = f2bfbits(a.w);
            t[4] = f2bfbits(b.x); t[5] = f2bfbits(b.y);
            t[6] = f2bfbits(b.z); t[7] = f2bfbits(b.w);
            *(uint4*)(dst + i) = *(const uint4*)t;
        } else {
            *(uint4*)(dst + i) = *(const uint4*)((const unsigned short*)src + off);
        }
    }
}

// ---------------------------------------------------------------------------
// GEMM: Y[m,n] = sum_k X[m,k]*W[n,k] + bias[n].
// vt_out=1: write transposed per-head layout Y_T[(b*H+h)*HD + hd][s] for V.
// flex_out=1: write fp32 if *flagp else bf16 (final output).
// ---------------------------------------------------------------------------
__launch_bounds__(256, 2)
__global__ void gemm_bias(const bf16* __restrict__ X, const bf16* __restrict__ W,
                          const bf16* __restrict__ bias, void* __restrict__ Yv,
                          const int* __restrict__ flagp, int flex_out, int vt_out)
{
    const int LDT = 264;
    __shared__ __align__(16) unsigned short xs[64 * 264];
    __shared__ __align__(16) unsigned short ws[64 * 264];
    const int t  = threadIdx.x;
    const int m0 = blockIdx.y * 64;
    const int n0 = blockIdx.x * 64;

    for (int i = 0; i < 8; ++i) {
        int c = t + i * 256;
        int row = c >> 5, col = (c & 31) * 8;
        *(uint4*)&xs[row * LDT + col] = *(const uint4*)(X + (size_t)(m0 + row) * DD + col);
        *(uint4*)&ws[row * LDT + col] = *(const uint4*)(W + (size_t)(n0 + row) * DD + col);
    }
    __syncthreads();

    const int w = t >> 6, lane = t & 63;
    const int lrow = lane & 15, lk = (lane >> 4) * 8, rgrp = (lane >> 4) * 4;
    floatx4 acc[4] = {};
    const unsigned short* ax = &xs[(w * 16 + lrow) * LDT + lk];
    for (int kt = 0; kt < 8; ++kt) {
        short8 a = *(const short8*)(ax + kt * 32);
        #pragma unroll
        for (int j = 0; j < 4; ++j) {
            short8 b = *(const short8*)&ws[(j * 16 + lrow) * LDT + kt * 32 + lk];
            acc[j] = __builtin_amdgcn_mfma_f32_16x16x32_bf16(a, b, acc[j], 0, 0, 0);
        }
    }

    if (vt_out) {
        // transpose 64x64 tile in LDS (reuse xs), then coalesced rows along S
        __syncthreads();
        unsigned short* ts = xs;
        #pragma unroll
        for (int j = 0; j < 4; ++j) {
            float bv = __bfloat162float(bias[n0 + j * 16 + lrow]);
            #pragma unroll
            for (int r = 0; r < 4; ++r)
                ts[(j * 16 + lrow) * 72 + w * 16 + rgrp + r] = f2bfbits(acc[j][r] + bv);
        }
        __syncthreads();
        const int bq = m0 >> 11, s0v = m0 & 2047, h = n0 >> 6;
        bf16* dstb = (bf16*)Yv + ((size_t)(bq * HH + h) * HD) * SS + s0v;
        for (int i = 0; i < 2; ++i) {
            int idx = t + i * 256, row = idx >> 3, ch = (idx & 7) * 8;
            *(uint4*)(dstb + (size_t)row * SS + ch) = *(const uint4*)&ts[row * 72 + ch];
        }
        return;
    }

    const bool f32o = flex_out && (*flagp != 0);
    #pragma unroll
    for (int j = 0; j < 4; ++j) {
        int col = n0 + j * 16 + lrow;
        float bv = __bfloat162float(bias[col]);
        #pragma unroll
        for (int r = 0; r < 4; ++r) {
            int row = m0 + w * 16 + rgrp + r;
            float val = acc[j][r] + bv;
            if (f32o) ((float*)Yv)[(size_t)row * DD + col] = val;
            else      ((bf16*)Yv)[(size_t)row * DD + col] = __float2bfloat16(val);
        }
    }
}

// ---------------------------------------------------------------------------
// Class-dependent key (unchanged this round).
// ---------------------------------------------------------------------------
__launch_bounds__(256, 2)
__global__ void classkey(const bf16* __restrict__ X, const bf16* __restrict__ Cond,
                         const bf16* __restrict__ Wk, const bf16* __restrict__ Wkb,
                         bf16* __restrict__ Kout)
{
    const int LDT = 264;
    __shared__ __align__(16) unsigned short xs[64 * 264];
    __shared__ __align__(16) unsigned short ws[64 * 264];
    __shared__ __align__(16) unsigned short conds[64 * 32];
    __shared__ __align__(16) unsigned short kbs[32 * 64];
    const int t  = threadIdx.x;
    const int m0 = blockIdx.y * 64;
    const int n0 = blockIdx.x * 64;

    for (int i = 0; i < 8; ++i) {
        int c = t + i * 256;
        int row = c >> 5, col = (c & 31) * 8;
        *(uint4*)&xs[row * LDT + col] = *(const uint4*)(X + (size_t)(m0 + row) * DD + col);
    }
    {
        int row = t >> 2, c8 = (t & 3) * 8;
        *(uint4*)&conds[row * 32 + c8] = *(const uint4*)(Cond + (size_t)(m0 + row) * CC + c8);
    }
    {
        int row = t >> 3, c8 = (t & 7) * 8;
        *(uint4*)&kbs[row * 64 + c8] = *(const uint4*)(Wkb + (size_t)row * DD + n0 + c8);
    }

    const int w = t >> 6, lane = t & 63;
    const int lrow = lane & 15, lk = (lane >> 4) * 8, rgrp = (lane >> 4) * 4;
    floatx4 acck[4] = {};

    for (int c = 0; c < CC; ++c) {
        __syncthreads();
        const bf16* Wc = Wk + (size_t)c * DD * DD;
        for (int i = 0; i < 8; ++i) {
            int ch = t + i * 256;
            int row = ch >> 5, col = (ch & 31) * 8;
            *(uint4*)&ws[row * LDT + col] = *(const uint4*)(Wc + (size_t)(n0 + row) * DD + col);
        }
        __syncthreads();

        floatx4 p[4] = {};
        const unsigned short* ax = &xs[(w * 16 + lrow) * LDT + lk];
        for (int kt = 0; kt < 8; ++kt) {
            short8 a = *(const short8*)(ax + kt * 32);
            #pragma unroll
            for (int j = 0; j < 4; ++j) {
                short8 b = *(const short8*)&ws[(j * 16 + lrow) * LDT + kt * 32 + lk];
                p[j] = __builtin_amdgcn_mfma_f32_16x16x32_bf16(a, b, p[j], 0, 0, 0);
            }
        }
        #pragma unroll
        for (int r = 0; r < 4; ++r) {
            float cv = bf2f(conds[(w * 16 + rgrp + r) * 32 + c]);
            #pragma unroll
            for (int j = 0; j < 4; ++j) acck[j][r] += cv * p[j][r];
        }
    }

    float kbv[4][4] = {};
    for (int c = 0; c < CC; ++c) {
        #pragma unroll
        for (int r = 0; r < 4; ++r) {
            float cf = bf2f(conds[(w * 16 + rgrp + r) * 32 + c]);
            #pragma unroll
            for (int j = 0; j < 4; ++j)
                kbv[j][r] += cf * bf2f(kbs[c * 64 + j * 16 + lrow]);
        }
    }
    #pragma unroll
    for (int j = 0; j < 4; ++j) {
        int col = n0 + j * 16 + lrow;
        #pragma unroll
        for (int r = 0; r < 4; ++r) {
            int row = m0 + w * 16 + rgrp + r;
            Kout[(size_t)row * DD + col] = __float2bfloat16(acck[j][r] + kbv[j][r]);
        }
    }
}

// ---------------------------------------------------------------------------
// Flash attention, S^T formulation. Block: 64 q rows, 4 waves (16 q each).
// S^T = K@Q^T in C-layout -> lane's q = lane&15, 16 keys in-register.
// Softmax: in-lane reduce + 2 shuffles. PV: mfma_16x16x16, P stays in regs.
// V pre-transposed to [b*H+h][hd][S] by the V-GEMM epilogue.
// ---------------------------------------------------------------------------
__launch_bounds__(256, 4)
__global__ void attn(const bf16* __restrict__ Q, const bf16* __restrict__ Kb,
                     const bf16* __restrict__ VT, bf16* __restrict__ O)
{
    const int LDQ = 72, LDV = 72;
    __shared__ __align__(16) unsigned short qs[64 * 72];
    __shared__ __align__(16) unsigned short ks[64 * 72];
    __shared__ __align__(16) unsigned short vt[64 * 72];   // [hd][key]
#if !HAVE_PV16
    __shared__ __align__(16) unsigned short ps[64 * 72];
#endif
    const int t  = threadIdx.x;
    const int bh = blockIdx.y;
    const int b  = bh >> 2, h = bh & 3;
    const int q0 = blockIdx.x * 64;
    const size_t base  = ((size_t)b * SS) * DD + h * HD;   // Q/K token-major
    const size_t vbase = (size_t)bh * HD * SS;             // V^T head-major

    for (int i = 0; i < 2; ++i) {
        int idx = t + i * 256, row = idx >> 3, ch = (idx & 7) * 8;
        *(uint4*)&qs[row * LDQ + ch] = *(const uint4*)(Q + base + (size_t)(q0 + row) * DD + ch);
    }

    const int w = t >> 6, lane = t & 63;
    const int lrow = lane & 15;      // q (softmax/col layout) and n-col (PV out)
    const int quad = lane >> 4;
    floatx4 acco[4] = {};            // O[q = w*16+quad*4+r][hd = jn*16+lrow]
    float mrun = -1e30f, lrun = 0.f; // state for q = lrow

    for (int kt = 0; kt < SS / 64; ++kt) {
        __syncthreads();
        int k0 = kt * 64;
        for (int i = 0; i < 2; ++i) {
            int idx = t + i * 256, row = idx >> 3, ch = (idx & 7) * 8;
            *(uint4*)&ks[row * LDQ + ch] = *(const uint4*)(Kb + base + (size_t)(k0 + row) * DD + ch);
            *(uint4*)&vt[row * LDV + ch] = *(const uint4*)(VT + vbase + (size_t)row * SS + k0 + ch);
        }
        __syncthreads();

        // S^T[key][q]: A = K rows (m=key), B = this wave's Q rows (n=q)
        floatx4 s[4] = {};
        #pragma unroll
        for (int k2 = 0; k2 < 2; ++k2) {
            short8 bq = *(const short8*)&qs[(w * 16 + lrow) * LDQ + k2 * 32 + quad * 8];
            #pragma unroll
            for (int j = 0; j < 4; ++j) {
                short8 ak = *(const short8*)&ks[(j * 16 + lrow) * LDQ + k2 * 32 + quad * 8];
                s[j] = __builtin_amdgcn_mfma_f32_16x16x32_bf16(ak, bq, s[j], 0, 0, 0);
            }
        }
        #pragma unroll
        for (int j = 0; j < 4; ++j)
            #pragma unroll
            for (int r = 0; r < 4; ++r) s[j][r] *= 0.125f;

        // online softmax for q=lrow; lane holds keys j*16+quad*4+r
        float mx = -1e30f;
        #pragma unroll
        for (int j = 0; j < 4; ++j)
            #pragma unroll
            for (int r = 0; r < 4; ++r) mx = fmaxf(mx, s[j][r]);
        mx = fmaxf(mx, __shfl_xor(mx, 16, 64));
        mx = fmaxf(mx, __shfl_xor(mx, 32, 64));
        float mnew  = fmaxf(mrun, mx);
        float alpha = __expf(mrun - mnew);
        float sum = 0.f;
        #pragma unroll
        for (int j = 0; j < 4; ++j)
            #pragma unroll
            for (int r = 0; r < 4; ++r) {
                float e = __expf(s[j][r] - mnew);
                s[j][r] = e; sum += e;
            }
        sum += __shfl_xor(sum, 16, 64);
        sum += __shfl_xor(sum, 32, 64);
        lrun = lrun * alpha + sum;
        mrun = mnew;

        // rescale O (row-layout q = quad*4+r) with alpha from col-layout lanes
        #pragma unroll
        for (int r = 0; r < 4; ++r) {
            float ar = __shfl(alpha, (quad << 4) + quad * 4 + r, 64);
            #pragma unroll
            for (int jn = 0; jn < 4; ++jn) acco[jn][r] *= ar;
        }

#if HAVE_PV16
        // P frags already in A-layout of 16x16x16: A[m=lrow][k=quad*4+i]
        #pragma unroll
        for (int j = 0; j < 4; ++j) {
            short4v p;
            p[0] = (short)f2bfbits(s[j][0]); p[1] = (short)f2bfbits(s[j][1]);
            p[2] = (short)f2bfbits(s[j][2]); p[3] = (short)f2bfbits(s[j][3]);
            #pragma unroll
            for (int jn = 0; jn < 4; ++jn) {
                short4v vv = *(const short4v*)&vt[(jn * 16 + lrow) * LDV + j * 16 + quad * 4];
                acco[jn] = MFMA_PV16(p, vv, acco[jn]);
            }
        }
#else
        // fallback: wave-private LDS round-trip, PV via 16x16x32
        #pragma unroll
        for (int j = 0; j < 4; ++j)
            #pragma unroll
            for (int r = 0; r < 4; ++r)
                ps[(w * 16 + lrow) * LDQ + j * 16 + quad * 4 + r] = f2bfbits(s[j][r]);
        #pragma unroll
        for (int k2 = 0; k2 < 2; ++k2) {
            short8 a = *(const short8*)&ps[(w * 16 + lrow) * LDQ + k2 * 32 + quad * 8];
            #pragma unroll
            for (int jn = 0; jn < 4; ++jn) {
                short8 bb = *(const short8*)&vt[(jn * 16 + lrow) * LDV + k2 * 32 + quad * 8];
                acco[jn] = __builtin_amdgcn_mfma_f32_16x16x32_bf16(a, bb, acco[jn], 0, 0, 0);
            }
        }
#endif
    }

    #pragma unroll
    for (int r = 0; r < 4; ++r) {
        float lr = __shfl(lrun, (quad << 4) + quad * 4 + r, 64);
        float inv = 1.0f / lr;
        int row = q0 + w * 16 + quad * 4 + r;
        #pragma unroll
        for (int jn = 0; jn < 4; ++jn)
            O[base + (size_t)row * DD + jn * 16 + lrow] = __float2bfloat16(acco[jn][r] * inv);
    }
}

// ---------------------------------------------------------------------------
extern "C" void kernel_launch(void* const* d_in, const int* in_sizes, int n_in,
                              void* d_out, int out_size, void* d_ws, size_t ws_size,
                              hipStream_t stream)
{
    int*  flag = (int*)d_ws;
    bf16* conv = (bf16*)((char*)d_ws + 256);

    const bf16* xb    = conv + P0;
    const bf16* condb = conv + P1;
    const bf16* wqw   = conv + P2;
    const bf16* wqb   = conv + P3;
    const bf16* wvw   = conv + P4;
    const bf16* wvb   = conv + P5;
    const bf16* wkw   = conv + P6;
    const bf16* wkb   = conv + P7;
    const bf16* wow   = conv + P8;
    const bf16* wob   = conv + P9;

    bf16* qb = conv + PTOT;
    bf16* kb = qb + (size_t)MTOT * DD;
    bf16* vb = kb + (size_t)MTOT * DD;   // V^T layout [b*H+h][hd][S]
    bf16* ob = vb + (size_t)MTOT * DD;

    dim3 blk(256);
    hipLaunchKernelGGL(detect_dtype, dim3(1), blk, 0, stream, d_in[0], flag);
    hipLaunchKernelGGL(convert_all, dim3((PTOT / 8 + 255) / 256), blk, 0, stream,
                       d_in[0], d_in[1], d_in[2], d_in[3], d_in[4],
                       d_in[5], d_in[6], d_in[7], d_in[8], d_in[9],
                       conv, flag);

    dim3 gg(DD / 64, MTOT / 64);
    hipLaunchKernelGGL(gemm_bias, gg, blk, 0, stream, xb, wqw, wqb, (void*)qb, flag, 0, 0);
    hipLaunchKernelGGL(gemm_bias, gg, blk, 0, stream, xb, wvw, wvb, (void*)vb, flag, 0, 1);
    hipLaunchKernelGGL(classkey,  gg, blk, 0, stream, xb, condb, wkw, wkb, kb);
    dim3 ga(SS / 64, BB * HH);
    hipLaunchKernelGGL(attn, ga, blk, 0, stream, qb, kb, vb, ob);
    hipLaunchKernelGGL(gemm_bias, gg, blk, 0, stream, ob, wow, wob, d_out, flag, 1, 0);
}

// Round 4
// 299.168 us; speedup vs baseline: 1.3845x; 1.1348x over previous
//
#include <hip/hip_runtime.h>
#include <hip/hip_bf16.h>

#define BB 8
#define SS 2048
#define DD 256
#define CC 32
#define HH 4
#define HD 64
#define MTOT (BB*SS)   // 16384 tokens

using bf16    = __hip_bfloat16;
using short8  = __attribute__((ext_vector_type(8))) short;
using short4v = __attribute__((ext_vector_type(4))) short;
using floatx4 = __attribute__((ext_vector_type(4))) float;

#if __has_builtin(__builtin_amdgcn_mfma_f32_16x16x16_bf16)
  #define MFMA_PV16(a,b,c) __builtin_amdgcn_mfma_f32_16x16x16_bf16(a,b,c,0,0,0)
  #define HAVE_PV16 1
#elif __has_builtin(__builtin_amdgcn_mfma_f32_16x16x16bf16_1k)
  #define MFMA_PV16(a,b,c) __builtin_amdgcn_mfma_f32_16x16x16bf16_1k(a,b,c,0,0,0)
  #define HAVE_PV16 1
#else
  #define HAVE_PV16 0
#endif

#if __has_builtin(__builtin_amdgcn_global_load_lds)
  #define HAVE_GLL 1
#else
  #define HAVE_GLL 0
#endif

__device__ inline float bf2f(unsigned short u) {
    union { unsigned int i; float f; } v; v.i = ((unsigned int)u) << 16; return v.f;
}
__device__ inline unsigned short f2bfbits(float f) {
    bf16 h = __float2bfloat16(f);
    return __builtin_bit_cast(unsigned short, h);
}

// --------------------------------------------------------------------------
#define N_X    (MTOT*DD)
#define N_COND (MTOT*CC)
#define N_WQW  (DD*DD)
#define N_WQB  (DD)
#define N_WVW  (DD*DD)
#define N_WVB  (DD)
#define N_WKW  (CC*DD*DD)
#define N_WKB  (CC*DD)
#define N_WOW  (DD*DD)
#define N_WOB  (DD)
#define P0 0
#define P1 (P0+N_X)
#define P2 (P1+N_COND)
#define P3 (P2+N_WQW)
#define P4 (P3+N_WQB)
#define P5 (P4+N_WVW)
#define P6 (P5+N_WVB)
#define P7 (P6+N_WKW)
#define P8 (P7+N_WKB)
#define P9 (P8+N_WOW)
#define PTOT (P9+N_WOB)

// --------------------------------------------------------------------------
__global__ void detect_dtype(const void* x, int* flag)
{
    __shared__ int total;
    if (threadIdx.x == 0) total = 0;
    __syncthreads();
    const float* xf = (const float*)x;
    int cnt = 0;
    for (int i = threadIdx.x; i < 4096; i += 256) {
        float v = fabsf(xf[i]);
        if (v == v && v > 1e-4f && v < 1e4f) cnt++;
    }
    atomicAdd(&total, cnt);
    __syncthreads();
    if (threadIdx.x == 0) *flag = (total > 2048) ? 1 : 0;
}

__global__ void convert_all(const void* s0, const void* s1, const void* s2,
                            const void* s3, const void* s4, const void* s5,
                            const void* s6, const void* s7, const void* s8,
                            const void* s9, bf16* dst, const int* flagp)
{
    const bool f32 = (*flagp != 0);
    size_t i = ((size_t)blockIdx.x * 256 + threadIdx.x) * 8;
    const size_t stride = (size_t)gridDim.x * 256 * 8;
    for (; i < (size_t)PTOT; i += stride) {
        const void* src; size_t off;
        if      (i < P1) { src = s0; off = i - P0; }
        else if (i < P2) { src = s1; off = i - P1; }
        else if (i < P3) { src = s2; off = i - P2; }
        else if (i < P4) { src = s3; off = i - P3; }
        else if (i < P5) { src = s4; off = i - P4; }
        else if (i < P6) { src = s5; off = i - P5; }
        else if (i < P7) { src = s6; off = i - P6; }
        else if (i < P8) { src = s7; off = i - P7; }
        else if (i < P9) { src = s8; off = i - P8; }
        else             { src = s9; off = i - P9; }
        if (f32) {
            const float* s = (const float*)src + off;
            float4 a = *(const float4*)(s);
            float4 b = *(const float4*)(s + 4);
            __align__(16) unsigned short t[8];
            t[0] = f2bfbits(a.x); t[1] = f2bfbits(a.y);
            t[2] = f2bfbits(a.z); t[3] = f2bfbits(a.w);
            t[4] = f2bfbits(b.x); t[5] = f2bfbits(b.y);
            t[6] = f2bfbits(b.z); t[7] = f2bfbits(b.w);
            *(uint4*)(dst + i) = *(const uint4*)t;
        } else {
            *(uint4*)(dst + i) = *(const uint4*)((const unsigned short*)src + off);
        }
    }
}

// ---------------------------------------------------------------------------
// GEMM: Y[m,n] = sum_k X[m,k]*W[n,k] + bias[n].  (unchanged from R3)
// ---------------------------------------------------------------------------
__launch_bounds__(256, 2)
__global__ void gemm_bias(const bf16* __restrict__ X, const bf16* __restrict__ W,
                          const bf16* __restrict__ bias, void* __restrict__ Yv,
                          const int* __restrict__ flagp, int flex_out, int vt_out)
{
    const int LDT = 264;
    __shared__ __align__(16) unsigned short xs[64 * 264];
    __shared__ __align__(16) unsigned short ws[64 * 264];
    const int t  = threadIdx.x;
    const int m0 = blockIdx.y * 64;
    const int n0 = blockIdx.x * 64;

    for (int i = 0; i < 8; ++i) {
        int c = t + i * 256;
        int row = c >> 5, col = (c & 31) * 8;
        *(uint4*)&xs[row * LDT + col] = *(const uint4*)(X + (size_t)(m0 + row) * DD + col);
        *(uint4*)&ws[row * LDT + col] = *(const uint4*)(W + (size_t)(n0 + row) * DD + col);
    }
    __syncthreads();

    const int w = t >> 6, lane = t & 63;
    const int lrow = lane & 15, lk = (lane >> 4) * 8, rgrp = (lane >> 4) * 4;
    floatx4 acc[4] = {};
    const unsigned short* ax = &xs[(w * 16 + lrow) * LDT + lk];
    for (int kt = 0; kt < 8; ++kt) {
        short8 a = *(const short8*)(ax + kt * 32);
        #pragma unroll
        for (int j = 0; j < 4; ++j) {
            short8 b = *(const short8*)&ws[(j * 16 + lrow) * LDT + kt * 32 + lk];
            acc[j] = __builtin_amdgcn_mfma_f32_16x16x32_bf16(a, b, acc[j], 0, 0, 0);
        }
    }

    if (vt_out) {
        __syncthreads();
        unsigned short* ts = xs;
        #pragma unroll
        for (int j = 0; j < 4; ++j) {
            float bv = __bfloat162float(bias[n0 + j * 16 + lrow]);
            #pragma unroll
            for (int r = 0; r < 4; ++r)
                ts[(j * 16 + lrow) * 72 + w * 16 + rgrp + r] = f2bfbits(acc[j][r] + bv);
        }
        __syncthreads();
        const int bq = m0 >> 11, s0v = m0 & 2047, h = n0 >> 6;
        bf16* dstb = (bf16*)Yv + ((size_t)(bq * HH + h) * HD) * SS + s0v;
        for (int i = 0; i < 2; ++i) {
            int idx = t + i * 256, row = idx >> 3, ch = (idx & 7) * 8;
            *(uint4*)(dstb + (size_t)row * SS + ch) = *(const uint4*)&ts[row * 72 + ch];
        }
        return;
    }

    const bool f32o = flex_out && (*flagp != 0);
    #pragma unroll
    for (int j = 0; j < 4; ++j) {
        int col = n0 + j * 16 + lrow;
        float bv = __bfloat162float(bias[col]);
        #pragma unroll
        for (int r = 0; r < 4; ++r) {
            int row = m0 + w * 16 + rgrp + r;
            float val = acc[j][r] + bv;
            if (f32o) ((float*)Yv)[(size_t)row * DD + col] = val;
            else      ((bf16*)Yv)[(size_t)row * DD + col] = __float2bfloat16(val);
        }
    }
}

// ---------------------------------------------------------------------------
// Class-dependent key v2.
// Block: 512 thr (8 waves), 128 tokens x 64 f-cols. X tile lives in REGISTERS
// (8 x short8 per lane, reused across all 32 classes). Wk slices staged
// direct-to-LDS via global_load_lds (width 16) into a ping-pong buffer,
// prefetching class c+1 during compute of class c. Unpadded LDS layout with
// 16B-chunk XOR swizzle (chunk' = chunk ^ (row&7)) -> conflict-free b128
// reads, cacheline-internal on the global side (no coalescing loss).
// ---------------------------------------------------------------------------
__device__ inline void stage_ws(const bf16* __restrict__ Wc,
                                unsigned short* wsbuf, int w, int lane)
{
    #pragma unroll
    for (int i = 0; i < 4; ++i) {
        int r  = w * 8 + i * 2 + (lane >> 5);       // row 0..63 of the slice
        int cp = lane & 31;                          // LDS 16B-chunk index
        int cs = cp ^ (r & 7);                       // swizzled global chunk
        const bf16* src = Wc + (size_t)r * DD + cs * 8;
        unsigned short* dst = wsbuf + (size_t)(w * 8 + i * 2) * DD;  // wave-uniform
#if HAVE_GLL
        __builtin_amdgcn_global_load_lds(
            (const __attribute__((address_space(1))) void*)src,
            (__attribute__((address_space(3))) void*)dst, 16, 0, 0);
#else
        uint4 v = *(const uint4*)src;
        *(uint4*)(dst + (size_t)lane * 8) = v;
#endif
    }
}

__launch_bounds__(512, 4)
__global__ void classkey(const bf16* __restrict__ X, const bf16* __restrict__ Cond,
                         const bf16* __restrict__ Wk, const bf16* __restrict__ Wkb,
                         bf16* __restrict__ Kout)
{
    __shared__ __align__(16) unsigned short ws[2][64 * 256];   // 64 KB ping-pong
    __shared__ __align__(16) unsigned short conds[128 * 32];   // 8 KB
    __shared__ __align__(16) unsigned short kbs[32 * 64];      // 4 KB
    const int t    = threadIdx.x;
    const int w    = t >> 6;            // wave 0..7
    const int lane = t & 63;
    const int r16  = lane & 15;
    const int quad = lane >> 4;
    const int m0   = blockIdx.y * 128;
    const int n0   = blockIdx.x * 64;

    // cond tile 128x32 (one uint4 per thread)
    {
        int row = t >> 2, c8 = (t & 3) * 8;
        *(uint4*)&conds[row * 32 + c8] = *(const uint4*)(Cond + (size_t)(m0 + row) * CC + c8);
    }
    // Wk_b slice 32x64
    if (t < 256) {
        int row = t >> 3, c8 = (t & 7) * 8;
        *(uint4*)&kbs[row * 64 + c8] = *(const uint4*)(Wkb + (size_t)row * DD + n0 + c8);
    }

    // X rows for this wave -> registers: A[m=r16][k = kt*32 + quad*8 + i]
    short8 xa[8];
    {
        const bf16* xrow = X + (size_t)(m0 + w * 16 + r16) * DD + quad * 8;
        #pragma unroll
        for (int kt = 0; kt < 8; ++kt)
            xa[kt] = *(const short8*)(xrow + kt * 32);
    }

    // prefetch class 0 into buffer 0
    stage_ws(Wk + (size_t)n0 * DD, &ws[0][0], w, lane);

    floatx4 acck[4] = {};
    for (int c = 0; c < CC; ++c) {
        __syncthreads();   // vmcnt(0) drain: buf[c&1] staged; buf[(c+1)&1] free
        if (c + 1 < CC)
            stage_ws(Wk + (size_t)(c + 1) * DD * DD + (size_t)n0 * DD,
                     &ws[(c + 1) & 1][0], w, lane);

        const unsigned short* wb = &ws[c & 1][0];
        floatx4 p[4] = {};
        #pragma unroll
        for (int kt = 0; kt < 8; ++kt) {
            short8 a = xa[kt];
            #pragma unroll
            for (int j = 0; j < 4; ++j) {
                // B[n = j*16+r16][k = kt*32+quad*8+i]; chunk (kt*4+quad)^(r16&7)
                short8 b = *(const short8*)&wb[(j * 16 + r16) * DD +
                                               (((kt * 4 + quad) ^ (r16 & 7)) << 3)];
                p[j] = __builtin_amdgcn_mfma_f32_16x16x32_bf16(a, b, p[j], 0, 0, 0);
            }
        }
        #pragma unroll
        for (int r = 0; r < 4; ++r) {
            float cv = bf2f(conds[(w * 16 + quad * 4 + r) * 32 + c]);
            #pragma unroll
            for (int j = 0; j < 4; ++j) acck[j][r] += cv * p[j][r];
        }
    }

    // bias: sum_c cond[row,c] * Wkb[c,col]
    float kbv[4][4] = {};
    for (int c = 0; c < CC; ++c) {
        #pragma unroll
        for (int r = 0; r < 4; ++r) {
            float cf = bf2f(conds[(w * 16 + quad * 4 + r) * 32 + c]);
            #pragma unroll
            for (int j = 0; j < 4; ++j)
                kbv[j][r] += cf * bf2f(kbs[c * 64 + j * 16 + r16]);
        }
    }
    #pragma unroll
    for (int j = 0; j < 4; ++j) {
        int col = n0 + j * 16 + r16;
        #pragma unroll
        for (int r = 0; r < 4; ++r) {
            int row = m0 + w * 16 + quad * 4 + r;
            Kout[(size_t)row * DD + col] = __float2bfloat16(acck[j][r] + kbv[j][r]);
        }
    }
}

// ---------------------------------------------------------------------------
// Flash attention, S^T formulation (unchanged from R3).
// ---------------------------------------------------------------------------
__launch_bounds__(256, 4)
__global__ void attn(const bf16* __restrict__ Q, const bf16* __restrict__ Kb,
                     const bf16* __restrict__ VT, bf16* __restrict__ O)
{
    const int LDQ = 72, LDV = 72;
    __shared__ __align__(16) unsigned short qs[64 * 72];
    __shared__ __align__(16) unsigned short ks[64 * 72];
    __shared__ __align__(16) unsigned short vt[64 * 72];
#if !HAVE_PV16
    __shared__ __align__(16) unsigned short ps[64 * 72];
#endif
    const int t  = threadIdx.x;
    const int bh = blockIdx.y;
    const int b  = bh >> 2, h = bh & 3;
    const int q0 = blockIdx.x * 64;
    const size_t base  = ((size_t)b * SS) * DD + h * HD;
    const size_t vbase = (size_t)bh * HD * SS;

    for (int i = 0; i < 2; ++i) {
        int idx = t + i * 256, row = idx >> 3, ch = (idx & 7) * 8;
        *(uint4*)&qs[row * LDQ + ch] = *(const uint4*)(Q + base + (size_t)(q0 + row) * DD + ch);
    }

    const int w = t >> 6, lane = t & 63;
    const int lrow = lane & 15;
    const int quad = lane >> 4;
    floatx4 acco[4] = {};
    float mrun = -1e30f, lrun = 0.f;

    for (int kt = 0; kt < SS / 64; ++kt) {
        __syncthreads();
        int k0 = kt * 64;
        for (int i = 0; i < 2; ++i) {
            int idx = t + i * 256, row = idx >> 3, ch = (idx & 7) * 8;
            *(uint4*)&ks[row * LDQ + ch] = *(const uint4*)(Kb + base + (size_t)(k0 + row) * DD + ch);
            *(uint4*)&vt[row * LDV + ch] = *(const uint4*)(VT + vbase + (size_t)row * SS + k0 + ch);
        }
        __syncthreads();

        floatx4 s[4] = {};
        #pragma unroll
        for (int k2 = 0; k2 < 2; ++k2) {
            short8 bq = *(const short8*)&qs[(w * 16 + lrow) * LDQ + k2 * 32 + quad * 8];
            #pragma unroll
            for (int j = 0; j < 4; ++j) {
                short8 ak = *(const short8*)&ks[(j * 16 + lrow) * LDQ + k2 * 32 + quad * 8];
                s[j] = __builtin_amdgcn_mfma_f32_16x16x32_bf16(ak, bq, s[j], 0, 0, 0);
            }
        }
        #pragma unroll
        for (int j = 0; j < 4; ++j)
            #pragma unroll
            for (int r = 0; r < 4; ++r) s[j][r] *= 0.125f;

        float mx = -1e30f;
        #pragma unroll
        for (int j = 0; j < 4; ++j)
            #pragma unroll
            for (int r = 0; r < 4; ++r) mx = fmaxf(mx, s[j][r]);
        mx = fmaxf(mx, __shfl_xor(mx, 16, 64));
        mx = fmaxf(mx, __shfl_xor(mx, 32, 64));
        float mnew  = fmaxf(mrun, mx);
        float alpha = __expf(mrun - mnew);
        float sum = 0.f;
        #pragma unroll
        for (int j = 0; j < 4; ++j)
            #pragma unroll
            for (int r = 0; r < 4; ++r) {
                float e = __expf(s[j][r] - mnew);
                s[j][r] = e; sum += e;
            }
        sum += __shfl_xor(sum, 16, 64);
        sum += __shfl_xor(sum, 32, 64);
        lrun = lrun * alpha + sum;
        mrun = mnew;

        #pragma unroll
        for (int r = 0; r < 4; ++r) {
            float ar = __shfl(alpha, (quad << 4) + quad * 4 + r, 64);
            #pragma unroll
            for (int jn = 0; jn < 4; ++jn) acco[jn][r] *= ar;
        }

#if HAVE_PV16
        #pragma unroll
        for (int j = 0; j < 4; ++j) {
            short4v p;
            p[0] = (short)f2bfbits(s[j][0]); p[1] = (short)f2bfbits(s[j][1]);
            p[2] = (short)f2bfbits(s[j][2]); p[3] = (short)f2bfbits(s[j][3]);
            #pragma unroll
            for (int jn = 0; jn < 4; ++jn) {
                short4v vv = *(const short4v*)&vt[(jn * 16 + lrow) * LDV + j * 16 + quad * 4];
                acco[jn] = MFMA_PV16(p, vv, acco[jn]);
            }
        }
#else
        #pragma unroll
        for (int j = 0; j < 4; ++j)
            #pragma unroll
            for (int r = 0; r < 4; ++r)
                ps[(w * 16 + lrow) * LDQ + j * 16 + quad * 4 + r] = f2bfbits(s[j][r]);
        #pragma unroll
        for (int k2 = 0; k2 < 2; ++k2) {
            short8 a = *(const short8*)&ps[(w * 16 + lrow) * LDQ + k2 * 32 + quad * 8];
            #pragma unroll
            for (int jn = 0; jn < 4; ++jn) {
                short8 bb = *(const short8*)&vt[(jn * 16 + lrow) * LDV + k2 * 32 + quad * 8];
                acco[jn] = __builtin_amdgcn_mfma_f32_16x16x32_bf16(a, bb, acco[jn], 0, 0, 0);
            }
        }
#endif
    }

    #pragma unroll
    for (int r = 0; r < 4; ++r) {
        float lr = __shfl(lrun, (quad << 4) + quad * 4 + r, 64);
        float inv = 1.0f / lr;
        int row = q0 + w * 16 + quad * 4 + r;
        #pragma unroll
        for (int jn = 0; jn < 4; ++jn)
            O[base + (size_t)row * DD + jn * 16 + lrow] = __float2bfloat16(acco[jn][r] * inv);
    }
}

// ---------------------------------------------------------------------------
extern "C" void kernel_launch(void* const* d_in, const int* in_sizes, int n_in,
                              void* d_out, int out_size, void* d_ws, size_t ws_size,
                              hipStream_t stream)
{
    int*  flag = (int*)d_ws;
    bf16* conv = (bf16*)((char*)d_ws + 256);

    const bf16* xb    = conv + P0;
    const bf16* condb = conv + P1;
    const bf16* wqw   = conv + P2;
    const bf16* wqb   = conv + P3;
    const bf16* wvw   = conv + P4;
    const bf16* wvb   = conv + P5;
    const bf16* wkw   = conv + P6;
    const bf16* wkb   = conv + P7;
    const bf16* wow   = conv + P8;
    const bf16* wob   = conv + P9;

    bf16* qb = conv + PTOT;
    bf16* kb = qb + (size_t)MTOT * DD;
    bf16* vb = kb + (size_t)MTOT * DD;   // V^T layout [b*H+h][hd][S]
    bf16* ob = vb + (size_t)MTOT * DD;

    dim3 blk(256);
    hipLaunchKernelGGL(detect_dtype, dim3(1), blk, 0, stream, d_in[0], flag);
    hipLaunchKernelGGL(convert_all, dim3((PTOT / 8 + 255) / 256), blk, 0, stream,
                       d_in[0], d_in[1], d_in[2], d_in[3], d_in[4],
                       d_in[5], d_in[6], d_in[7], d_in[8], d_in[9],
                       conv, flag);

    dim3 gg(DD / 64, MTOT / 64);
    hipLaunchKernelGGL(gemm_bias, gg, blk, 0, stream, xb, wqw, wqb, (void*)qb, flag, 0, 0);
    hipLaunchKernelGGL(gemm_bias, gg, blk, 0, stream, xb, wvw, wvb, (void*)vb, flag, 0, 1);
    dim3 gck(DD / 64, MTOT / 128);       // (4, 128), 512-thread blocks
    hipLaunchKernelGGL(classkey, gck, dim3(512), 0, stream, xb, condb, wkw, wkb, kb);
    dim3 ga(SS / 64, BB * HH);
    hipLaunchKernelGGL(attn, ga, blk, 0, stream, qb, kb, vb, ob);
    hipLaunchKernelGGL(gemm_bias, gg, blk, 0, stream, ob, wow, wob, d_out, flag, 1, 0);
}

// Round 5
// 274.235 us; speedup vs baseline: 1.5103x; 1.0909x over previous
//
#include <hip/hip_runtime.h>
#include <hip/hip_bf16.h>

#define BB 8
#define SS 2048
#define DD 256
#define CC 32
#define HH 4
#define HD 64
#define MTOT (BB*SS)   // 16384 tokens

using bf16    = __hip_bfloat16;
using short8  = __attribute__((ext_vector_type(8))) short;
using short4v = __attribute__((ext_vector_type(4))) short;
using floatx4 = __attribute__((ext_vector_type(4))) float;

#if __has_builtin(__builtin_amdgcn_mfma_f32_16x16x16_bf16)
  #define MFMA_PV16(a,b,c) __builtin_amdgcn_mfma_f32_16x16x16_bf16(a,b,c,0,0,0)
  #define HAVE_PV16 1
#elif __has_builtin(__builtin_amdgcn_mfma_f32_16x16x16bf16_1k)
  #define MFMA_PV16(a,b,c) __builtin_amdgcn_mfma_f32_16x16x16bf16_1k(a,b,c,0,0,0)
  #define HAVE_PV16 1
#else
  #define HAVE_PV16 0
#endif

#if __has_builtin(__builtin_amdgcn_global_load_lds)
  #define HAVE_GLL 1
#else
  #define HAVE_GLL 0
#endif

__device__ inline float bf2f(unsigned short u) {
    union { unsigned int i; float f; } v; v.i = ((unsigned int)u) << 16; return v.f;
}
__device__ inline unsigned short f2bfbits(float f) {
    bf16 h = __float2bfloat16(f);
    return __builtin_bit_cast(unsigned short, h);
}

// --------------------------------------------------------------------------
#define N_X    (MTOT*DD)
#define N_COND (MTOT*CC)
#define N_WQW  (DD*DD)
#define N_WQB  (DD)
#define N_WVW  (DD*DD)
#define N_WVB  (DD)
#define N_WKW  (CC*DD*DD)
#define N_WKB  (CC*DD)
#define N_WOW  (DD*DD)
#define N_WOB  (DD)
#define P0 0
#define P1 (P0+N_X)
#define P2 (P1+N_COND)
#define P3 (P2+N_WQW)
#define P4 (P3+N_WQB)
#define P5 (P4+N_WVW)
#define P6 (P5+N_WVB)
#define P7 (P6+N_WKW)
#define P8 (P7+N_WKB)
#define P9 (P8+N_WOW)
#define PTOT (P9+N_WOB)

// --------------------------------------------------------------------------
__global__ void detect_dtype(const void* x, int* flag)
{
    __shared__ int total;
    if (threadIdx.x == 0) total = 0;
    __syncthreads();
    const float* xf = (const float*)x;
    int cnt = 0;
    for (int i = threadIdx.x; i < 4096; i += 256) {
        float v = fabsf(xf[i]);
        if (v == v && v > 1e-4f && v < 1e4f) cnt++;
    }
    atomicAdd(&total, cnt);
    __syncthreads();
    if (threadIdx.x == 0) *flag = (total > 2048) ? 1 : 0;
}

__global__ void convert_all(const void* s0, const void* s1, const void* s2,
                            const void* s3, const void* s4, const void* s5,
                            const void* s6, const void* s7, const void* s8,
                            const void* s9, bf16* dst, const int* flagp)
{
    const bool f32 = (*flagp != 0);
    size_t i = ((size_t)blockIdx.x * 256 + threadIdx.x) * 8;
    const size_t stride = (size_t)gridDim.x * 256 * 8;
    for (; i < (size_t)PTOT; i += stride) {
        const void* src; size_t off;
        if      (i < P1) { src = s0; off = i - P0; }
        else if (i < P2) { src = s1; off = i - P1; }
        else if (i < P3) { src = s2; off = i - P2; }
        else if (i < P4) { src = s3; off = i - P3; }
        else if (i < P5) { src = s4; off = i - P4; }
        else if (i < P6) { src = s5; off = i - P5; }
        else if (i < P7) { src = s6; off = i - P6; }
        else if (i < P8) { src = s7; off = i - P7; }
        else if (i < P9) { src = s8; off = i - P8; }
        else             { src = s9; off = i - P9; }
        if (f32) {
            const float* s = (const float*)src + off;
            float4 a = *(const float4*)(s);
            float4 b = *(const float4*)(s + 4);
            __align__(16) unsigned short t[8];
            t[0] = f2bfbits(a.x); t[1] = f2bfbits(a.y);
            t[2] = f2bfbits(a.z); t[3] = f2bfbits(a.w);
            t[4] = f2bfbits(b.x); t[5] = f2bfbits(b.y);
            t[6] = f2bfbits(b.z); t[7] = f2bfbits(b.w);
            *(uint4*)(dst + i) = *(const uint4*)t;
        } else {
            *(uint4*)(dst + i) = *(const uint4*)((const unsigned short*)src + off);
        }
    }
}

// ---------------------------------------------------------------------------
// GEMM: Y[m,n] = sum_k X[m,k]*W[n,k] + bias[n].  (unchanged)
// ---------------------------------------------------------------------------
__launch_bounds__(256, 2)
__global__ void gemm_bias(const bf16* __restrict__ X, const bf16* __restrict__ W,
                          const bf16* __restrict__ bias, void* __restrict__ Yv,
                          const int* __restrict__ flagp, int flex_out, int vt_out)
{
    const int LDT = 264;
    __shared__ __align__(16) unsigned short xs[64 * 264];
    __shared__ __align__(16) unsigned short ws[64 * 264];
    const int t  = threadIdx.x;
    const int m0 = blockIdx.y * 64;
    const int n0 = blockIdx.x * 64;

    for (int i = 0; i < 8; ++i) {
        int c = t + i * 256;
        int row = c >> 5, col = (c & 31) * 8;
        *(uint4*)&xs[row * LDT + col] = *(const uint4*)(X + (size_t)(m0 + row) * DD + col);
        *(uint4*)&ws[row * LDT + col] = *(const uint4*)(W + (size_t)(n0 + row) * DD + col);
    }
    __syncthreads();

    const int w = t >> 6, lane = t & 63;
    const int lrow = lane & 15, lk = (lane >> 4) * 8, rgrp = (lane >> 4) * 4;
    floatx4 acc[4] = {};
    const unsigned short* ax = &xs[(w * 16 + lrow) * LDT + lk];
    for (int kt = 0; kt < 8; ++kt) {
        short8 a = *(const short8*)(ax + kt * 32);
        #pragma unroll
        for (int j = 0; j < 4; ++j) {
            short8 b = *(const short8*)&ws[(j * 16 + lrow) * LDT + kt * 32 + lk];
            acc[j] = __builtin_amdgcn_mfma_f32_16x16x32_bf16(a, b, acc[j], 0, 0, 0);
        }
    }

    if (vt_out) {
        __syncthreads();
        unsigned short* ts = xs;
        #pragma unroll
        for (int j = 0; j < 4; ++j) {
            float bv = __bfloat162float(bias[n0 + j * 16 + lrow]);
            #pragma unroll
            for (int r = 0; r < 4; ++r)
                ts[(j * 16 + lrow) * 72 + w * 16 + rgrp + r] = f2bfbits(acc[j][r] + bv);
        }
        __syncthreads();
        const int bq = m0 >> 11, s0v = m0 & 2047, h = n0 >> 6;
        bf16* dstb = (bf16*)Yv + ((size_t)(bq * HH + h) * HD) * SS + s0v;
        for (int i = 0; i < 2; ++i) {
            int idx = t + i * 256, row = idx >> 3, ch = (idx & 7) * 8;
            *(uint4*)(dstb + (size_t)row * SS + ch) = *(const uint4*)&ts[row * 72 + ch];
        }
        return;
    }

    const bool f32o = flex_out && (*flagp != 0);
    #pragma unroll
    for (int j = 0; j < 4; ++j) {
        int col = n0 + j * 16 + lrow;
        float bv = __bfloat162float(bias[col]);
        #pragma unroll
        for (int r = 0; r < 4; ++r) {
            int row = m0 + w * 16 + rgrp + r;
            float val = acc[j][r] + bv;
            if (f32o) ((float*)Yv)[(size_t)row * DD + col] = val;
            else      ((bf16*)Yv)[(size_t)row * DD + col] = __float2bfloat16(val);
        }
    }
}

// ---------------------------------------------------------------------------
// Class-dependent key v2 (unchanged from R4 — validated).
// ---------------------------------------------------------------------------
__device__ inline void stage_ws(const bf16* __restrict__ Wc,
                                unsigned short* wsbuf, int w, int lane)
{
    #pragma unroll
    for (int i = 0; i < 4; ++i) {
        int r  = w * 8 + i * 2 + (lane >> 5);
        int cp = lane & 31;
        int cs = cp ^ (r & 7);
        const bf16* src = Wc + (size_t)r * DD + cs * 8;
        unsigned short* dst = wsbuf + (size_t)(w * 8 + i * 2) * DD;
#if HAVE_GLL
        __builtin_amdgcn_global_load_lds(
            (const __attribute__((address_space(1))) void*)src,
            (__attribute__((address_space(3))) void*)dst, 16, 0, 0);
#else
        uint4 v = *(const uint4*)src;
        *(uint4*)(dst + (size_t)lane * 8) = v;
#endif
    }
}

__launch_bounds__(512, 4)
__global__ void classkey(const bf16* __restrict__ X, const bf16* __restrict__ Cond,
                         const bf16* __restrict__ Wk, const bf16* __restrict__ Wkb,
                         bf16* __restrict__ Kout)
{
    __shared__ __align__(16) unsigned short ws[2][64 * 256];
    __shared__ __align__(16) unsigned short conds[128 * 32];
    __shared__ __align__(16) unsigned short kbs[32 * 64];
    const int t    = threadIdx.x;
    const int w    = t >> 6;
    const int lane = t & 63;
    const int r16  = lane & 15;
    const int quad = lane >> 4;
    const int m0   = blockIdx.y * 128;
    const int n0   = blockIdx.x * 64;

    {
        int row = t >> 2, c8 = (t & 3) * 8;
        *(uint4*)&conds[row * 32 + c8] = *(const uint4*)(Cond + (size_t)(m0 + row) * CC + c8);
    }
    if (t < 256) {
        int row = t >> 3, c8 = (t & 7) * 8;
        *(uint4*)&kbs[row * 64 + c8] = *(const uint4*)(Wkb + (size_t)row * DD + n0 + c8);
    }

    short8 xa[8];
    {
        const bf16* xrow = X + (size_t)(m0 + w * 16 + r16) * DD + quad * 8;
        #pragma unroll
        for (int kt = 0; kt < 8; ++kt)
            xa[kt] = *(const short8*)(xrow + kt * 32);
    }

    stage_ws(Wk + (size_t)n0 * DD, &ws[0][0], w, lane);

    floatx4 acck[4] = {};
    for (int c = 0; c < CC; ++c) {
        __syncthreads();
        if (c + 1 < CC)
            stage_ws(Wk + (size_t)(c + 1) * DD * DD + (size_t)n0 * DD,
                     &ws[(c + 1) & 1][0], w, lane);

        const unsigned short* wb = &ws[c & 1][0];
        floatx4 p[4] = {};
        #pragma unroll
        for (int kt = 0; kt < 8; ++kt) {
            short8 a = xa[kt];
            #pragma unroll
            for (int j = 0; j < 4; ++j) {
                short8 b = *(const short8*)&wb[(j * 16 + r16) * DD +
                                               (((kt * 4 + quad) ^ (r16 & 7)) << 3)];
                p[j] = __builtin_amdgcn_mfma_f32_16x16x32_bf16(a, b, p[j], 0, 0, 0);
            }
        }
        #pragma unroll
        for (int r = 0; r < 4; ++r) {
            float cv = bf2f(conds[(w * 16 + quad * 4 + r) * 32 + c]);
            #pragma unroll
            for (int j = 0; j < 4; ++j) acck[j][r] += cv * p[j][r];
        }
    }

    float kbv[4][4] = {};
    for (int c = 0; c < CC; ++c) {
        #pragma unroll
        for (int r = 0; r < 4; ++r) {
            float cf = bf2f(conds[(w * 16 + quad * 4 + r) * 32 + c]);
            #pragma unroll
            for (int j = 0; j < 4; ++j)
                kbv[j][r] += cf * bf2f(kbs[c * 64 + j * 16 + r16]);
        }
    }
    #pragma unroll
    for (int j = 0; j < 4; ++j) {
        int col = n0 + j * 16 + r16;
        #pragma unroll
        for (int r = 0; r < 4; ++r) {
            int row = m0 + w * 16 + quad * 4 + r;
            Kout[(size_t)row * DD + col] = __float2bfloat16(acck[j][r] + kbv[j][r]);
        }
    }
}

// ---------------------------------------------------------------------------
// Flash attention v2. Block: 128 q rows, 512 thr (8 waves, 16 q each).
// Q pre-scaled (1/8, exact) in registers. K tile [key][hd] and V^T tile
// [hd][key] staged via global_load_lds (16B) into ping-pong LDS buffers,
// prefetching tile kt+1 during compute of kt -> one barrier per tile.
// Unpadded 64-short rows + 16B-chunk XOR swizzle (chunk^(row&7), folded into
// the global source address) -> even bank distribution (8 words/bank for
// b128 frags, 4 words/bank for b64 vt frags) = conflict-free.
// ---------------------------------------------------------------------------
__device__ inline void stage_kv(const bf16* __restrict__ kRow,   // + r*DD
                                const bf16* __restrict__ vRow,   // + r*SS
                                unsigned short* kbuf, unsigned short* vbuf,
                                int w, int lane)
{
    int r  = w * 8 + (lane >> 3);
    int cs = (lane & 7) ^ (r & 7);
#if HAVE_GLL
    __builtin_amdgcn_global_load_lds(
        (const __attribute__((address_space(1))) void*)(kRow + (size_t)r * DD + cs * 8),
        (__attribute__((address_space(3))) void*)(kbuf + w * 512), 16, 0, 0);
    __builtin_amdgcn_global_load_lds(
        (const __attribute__((address_space(1))) void*)(vRow + (size_t)r * SS + cs * 8),
        (__attribute__((address_space(3))) void*)(vbuf + w * 512), 16, 0, 0);
#else
    *(uint4*)(kbuf + w * 512 + (size_t)lane * 8) = *(const uint4*)(kRow + (size_t)r * DD + cs * 8);
    *(uint4*)(vbuf + w * 512 + (size_t)lane * 8) = *(const uint4*)(vRow + (size_t)r * SS + cs * 8);
#endif
}

__launch_bounds__(512, 4)
__global__ void attn(const bf16* __restrict__ Q, const bf16* __restrict__ Kb,
                     const bf16* __restrict__ VT, bf16* __restrict__ O)
{
    __shared__ __align__(16) unsigned short ks[2][64 * 64];   // 16 KB ping-pong
    __shared__ __align__(16) unsigned short vt[2][64 * 64];   // 16 KB ping-pong
#if !HAVE_PV16
    __shared__ __align__(16) unsigned short ps[128 * 72];
#endif
    const int t    = threadIdx.x;
    const int w    = t >> 6;           // 0..7
    const int lane = t & 63;
    const int r16  = lane & 15;
    const int quad = lane >> 4;
    const int bh   = blockIdx.y;
    const int b    = bh >> 2, h = bh & 3;
    const int q0   = blockIdx.x * 128;
    const size_t base  = ((size_t)b * SS) * DD + h * HD;   // Q/K token-major
    const size_t vbase = (size_t)bh * HD * SS;             // V^T head-major

    // Q rows -> registers, pre-scaled by 1/sqrt(64)=0.125 (exact in bf16)
    short8 qa[2];
    {
        const bf16* qrow = Q + base + (size_t)(q0 + w * 16 + r16) * DD + quad * 8;
        #pragma unroll
        for (int k2 = 0; k2 < 2; ++k2) {
            short8 raw = *(const short8*)(qrow + k2 * 32);
            short8 sc;
            #pragma unroll
            for (int e = 0; e < 8; ++e)
                sc[e] = (short)f2bfbits(bf2f((unsigned short)raw[e]) * 0.125f);
            qa[k2] = sc;
        }
    }

    // prefetch tile 0
    stage_kv(Kb + base, VT + vbase, &ks[0][0], &vt[0][0], w, lane);

    floatx4 acco[4] = {};
    float mrun = -1e30f, lrun = 0.f;

    for (int kt = 0; kt < SS / 64; ++kt) {
        __syncthreads();   // drains prefetch of buf[kt&1]; prev reads of buf[(kt+1)&1] done
        if (kt + 1 < SS / 64)
            stage_kv(Kb + base + (size_t)(kt + 1) * 64 * DD,
                     VT + vbase + (size_t)(kt + 1) * 64,
                     &ks[(kt + 1) & 1][0], &vt[(kt + 1) & 1][0], w, lane);

        const unsigned short* kbuf = &ks[kt & 1][0];
        const unsigned short* vbuf = &vt[kt & 1][0];

        // S^T[key][q] = K @ Q^T (pre-scaled)
        floatx4 s[4] = {};
        #pragma unroll
        for (int k2 = 0; k2 < 2; ++k2) {
            short8 bq = qa[k2];
            #pragma unroll
            for (int j = 0; j < 4; ++j) {
                short8 ak = *(const short8*)&kbuf[(j * 16 + r16) * 64 +
                                                  (((k2 * 4 + quad) ^ (r16 & 7)) << 3)];
                s[j] = __builtin_amdgcn_mfma_f32_16x16x32_bf16(ak, bq, s[j], 0, 0, 0);
            }
        }

        // online softmax for q=r16; lane holds keys j*16+quad*4+r
        float mx = -1e30f;
        #pragma unroll
        for (int j = 0; j < 4; ++j)
            #pragma unroll
            for (int r = 0; r < 4; ++r) mx = fmaxf(mx, s[j][r]);
        mx = fmaxf(mx, __shfl_xor(mx, 16, 64));
        mx = fmaxf(mx, __shfl_xor(mx, 32, 64));
        float mnew  = fmaxf(mrun, mx);
        float alpha = __expf(mrun - mnew);
        float sum = 0.f;
        #pragma unroll
        for (int j = 0; j < 4; ++j)
            #pragma unroll
            for (int r = 0; r < 4; ++r) {
                float e = __expf(s[j][r] - mnew);
                s[j][r] = e; sum += e;
            }
        sum += __shfl_xor(sum, 16, 64);
        sum += __shfl_xor(sum, 32, 64);
        lrun = lrun * alpha + sum;
        mrun = mnew;

        // rescale O (row-layout q = quad*4+r) with alpha from col-layout lanes
        #pragma unroll
        for (int r = 0; r < 4; ++r) {
            float ar = __shfl(alpha, (quad << 4) + quad * 4 + r, 64);
            #pragma unroll
            for (int jn = 0; jn < 4; ++jn) acco[jn][r] *= ar;
        }

#if HAVE_PV16
        // P frags already in A-layout of 16x16x16: A[m=r16][k=quad*4+i]
        #pragma unroll
        for (int j = 0; j < 4; ++j) {
            short4v p;
            p[0] = (short)f2bfbits(s[j][0]); p[1] = (short)f2bfbits(s[j][1]);
            p[2] = (short)f2bfbits(s[j][2]); p[3] = (short)f2bfbits(s[j][3]);
            #pragma unroll
            for (int jn = 0; jn < 4; ++jn) {
                // V^T[hd = jn*16+r16][key = j*16+quad*4+i]
                short4v vv = *(const short4v*)&vbuf[(jn * 16 + r16) * 64 +
                                                    ((((j * 2) + (quad >> 1)) ^ (r16 & 7)) << 3) +
                                                    (quad & 1) * 4];
                acco[jn] = MFMA_PV16(p, vv, acco[jn]);
            }
        }
#else
        #pragma unroll
        for (int j = 0; j < 4; ++j)
            #pragma unroll
            for (int r = 0; r < 4; ++r)
                ps[(w * 16 + r16) * 72 + j * 16 + quad * 4 + r] = f2bfbits(s[j][r]);
        #pragma unroll
        for (int k2 = 0; k2 < 2; ++k2) {
            short8 a = *(const short8*)&ps[(w * 16 + r16) * 72 + k2 * 32 + quad * 8];
            #pragma unroll
            for (int jn = 0; jn < 4; ++jn) {
                short8 bb = *(const short8*)&vbuf[(jn * 16 + r16) * 64 +
                                                  (((k2 * 4 + quad) ^ (r16 & 7)) << 3)];
                acco[jn] = __builtin_amdgcn_mfma_f32_16x16x32_bf16(a, bb, acco[jn], 0, 0, 0);
            }
        }
#endif
    }

    #pragma unroll
    for (int r = 0; r < 4; ++r) {
        float lr = __shfl(lrun, (quad << 4) + quad * 4 + r, 64);
        float inv = 1.0f / lr;
        int row = q0 + w * 16 + quad * 4 + r;
        #pragma unroll
        for (int jn = 0; jn < 4; ++jn)
            O[base + (size_t)row * DD + jn * 16 + r16] = __float2bfloat16(acco[jn][r] * inv);
    }
}

// ---------------------------------------------------------------------------
extern "C" void kernel_launch(void* const* d_in, const int* in_sizes, int n_in,
                              void* d_out, int out_size, void* d_ws, size_t ws_size,
                              hipStream_t stream)
{
    int*  flag = (int*)d_ws;
    bf16* conv = (bf16*)((char*)d_ws + 256);

    const bf16* xb    = conv + P0;
    const bf16* condb = conv + P1;
    const bf16* wqw   = conv + P2;
    const bf16* wqb   = conv + P3;
    const bf16* wvw   = conv + P4;
    const bf16* wvb   = conv + P5;
    const bf16* wkw   = conv + P6;
    const bf16* wkb   = conv + P7;
    const bf16* wow   = conv + P8;
    const bf16* wob   = conv + P9;

    bf16* qb = conv + PTOT;
    bf16* kb = qb + (size_t)MTOT * DD;
    bf16* vb = kb + (size_t)MTOT * DD;   // V^T layout [b*H+h][hd][S]
    bf16* ob = vb + (size_t)MTOT * DD;

    dim3 blk(256);
    hipLaunchKernelGGL(detect_dtype, dim3(1), blk, 0, stream, d_in[0], flag);
    hipLaunchKernelGGL(convert_all, dim3((PTOT / 8 + 255) / 256), blk, 0, stream,
                       d_in[0], d_in[1], d_in[2], d_in[3], d_in[4],
                       d_in[5], d_in[6], d_in[7], d_in[8], d_in[9],
                       conv, flag);

    dim3 gg(DD / 64, MTOT / 64);
    hipLaunchKernelGGL(gemm_bias, gg, blk, 0, stream, xb, wqw, wqb, (void*)qb, flag, 0, 0);
    hipLaunchKernelGGL(gemm_bias, gg, blk, 0, stream, xb, wvw, wvb, (void*)vb, flag, 0, 1);
    dim3 gck(DD / 64, MTOT / 128);       // (4, 128), 512-thread blocks
    hipLaunchKernelGGL(classkey, gck, dim3(512), 0, stream, xb, condb, wkw, wkb, kb);
    dim3 ga(SS / 128, BB * HH);          // (16, 32), 512-thread blocks
    hipLaunchKernelGGL(attn, ga, dim3(512), 0, stream, qb, kb, vb, ob);
    hipLaunchKernelGGL(gemm_bias, gg, blk, 0, stream, ob, wow, wob, d_out, flag, 1, 0);
}

// Round 6
// 259.990 us; speedup vs baseline: 1.5931x; 1.0548x over previous
//
#include <hip/hip_runtime.h>
#include <hip/hip_bf16.h>

#define BB 8
#define SS 2048
#define DD 256
#define CC 32
#define HH 4
#define HD 64
#define MTOT (BB*SS)   // 16384 tokens

using bf16    = __hip_bfloat16;
using short8  = __attribute__((ext_vector_type(8))) short;
using short4v = __attribute__((ext_vector_type(4))) short;
using floatx4 = __attribute__((ext_vector_type(4))) float;

#if __has_builtin(__builtin_amdgcn_mfma_f32_16x16x16_bf16)
  #define MFMA_PV16(a,b,c) __builtin_amdgcn_mfma_f32_16x16x16_bf16(a,b,c,0,0,0)
  #define HAVE_PV16 1
#elif __has_builtin(__builtin_amdgcn_mfma_f32_16x16x16bf16_1k)
  #define MFMA_PV16(a,b,c) __builtin_amdgcn_mfma_f32_16x16x16bf16_1k(a,b,c,0,0,0)
  #define HAVE_PV16 1
#else
  #define HAVE_PV16 0
#endif

#if __has_builtin(__builtin_amdgcn_global_load_lds)
  #define HAVE_GLL 1
#else
  #define HAVE_GLL 0
#endif

__device__ inline float bf2f(unsigned short u) {
    union { unsigned int i; float f; } v; v.i = ((unsigned int)u) << 16; return v.f;
}
__device__ inline unsigned short f2bfbits(float f) {
    bf16 h = __float2bfloat16(f);
    return __builtin_bit_cast(unsigned short, h);
}

// --------------------------------------------------------------------------
#define N_X    (MTOT*DD)
#define N_COND (MTOT*CC)
#define N_WQW  (DD*DD)
#define N_WQB  (DD)
#define N_WVW  (DD*DD)
#define N_WVB  (DD)
#define N_WKW  (CC*DD*DD)
#define N_WKB  (CC*DD)
#define N_WOW  (DD*DD)
#define N_WOB  (DD)
#define P0 0
#define P1 (P0+N_X)
#define P2 (P1+N_COND)
#define P3 (P2+N_WQW)
#define P4 (P3+N_WQB)
#define P5 (P4+N_WVW)
#define P6 (P5+N_WVB)
#define P7 (P6+N_WKW)
#define P8 (P7+N_WKB)
#define P9 (P8+N_WOW)
#define PTOT (P9+N_WOB)

// --------------------------------------------------------------------------
__global__ void detect_dtype(const void* x, int* flag)
{
    __shared__ int total;
    if (threadIdx.x == 0) total = 0;
    __syncthreads();
    const float* xf = (const float*)x;
    int cnt = 0;
    for (int i = threadIdx.x; i < 4096; i += 256) {
        float v = fabsf(xf[i]);
        if (v == v && v > 1e-4f && v < 1e4f) cnt++;
    }
    atomicAdd(&total, cnt);
    __syncthreads();
    if (threadIdx.x == 0) *flag = (total > 2048) ? 1 : 0;
}

__global__ void convert_all(const void* s0, const void* s1, const void* s2,
                            const void* s3, const void* s4, const void* s5,
                            const void* s6, const void* s7, const void* s8,
                            const void* s9, bf16* dst, const int* flagp)
{
    const bool f32 = (*flagp != 0);
    size_t i = ((size_t)blockIdx.x * 256 + threadIdx.x) * 8;
    const size_t stride = (size_t)gridDim.x * 256 * 8;
    for (; i < (size_t)PTOT; i += stride) {
        const void* src; size_t off;
        if      (i < P1) { src = s0; off = i - P0; }
        else if (i < P2) { src = s1; off = i - P1; }
        else if (i < P3) { src = s2; off = i - P2; }
        else if (i < P4) { src = s3; off = i - P3; }
        else if (i < P5) { src = s4; off = i - P4; }
        else if (i < P6) { src = s5; off = i - P5; }
        else if (i < P7) { src = s6; off = i - P6; }
        else if (i < P8) { src = s7; off = i - P7; }
        else if (i < P9) { src = s8; off = i - P8; }
        else             { src = s9; off = i - P9; }
        if (f32) {
            const float* s = (const float*)src + off;
            float4 a = *(const float4*)(s);
            float4 b = *(const float4*)(s + 4);
            __align__(16) unsigned short t[8];
            t[0] = f2bfbits(a.x); t[1] = f2bfbits(a.y);
            t[2] = f2bfbits(a.z); t[3] = f2bfbits(a.w);
            t[4] = f2bfbits(b.x); t[5] = f2bfbits(b.y);
            t[6] = f2bfbits(b.z); t[7] = f2bfbits(b.w);
            *(uint4*)(dst + i) = *(const uint4*)t;
        } else {
            *(uint4*)(dst + i) = *(const uint4*)((const unsigned short*)src + off);
        }
    }
}

// ---------------------------------------------------------------------------
// GEMM: Y[m,n] = sum_k X[m,k]*W[n,k] + bias[n].  (unchanged)
// ---------------------------------------------------------------------------
__launch_bounds__(256, 2)
__global__ void gemm_bias(const bf16* __restrict__ X, const bf16* __restrict__ W,
                          const bf16* __restrict__ bias, void* __restrict__ Yv,
                          const int* __restrict__ flagp, int flex_out, int vt_out)
{
    const int LDT = 264;
    __shared__ __align__(16) unsigned short xs[64 * 264];
    __shared__ __align__(16) unsigned short ws[64 * 264];
    const int t  = threadIdx.x;
    const int m0 = blockIdx.y * 64;
    const int n0 = blockIdx.x * 64;

    for (int i = 0; i < 8; ++i) {
        int c = t + i * 256;
        int row = c >> 5, col = (c & 31) * 8;
        *(uint4*)&xs[row * LDT + col] = *(const uint4*)(X + (size_t)(m0 + row) * DD + col);
        *(uint4*)&ws[row * LDT + col] = *(const uint4*)(W + (size_t)(n0 + row) * DD + col);
    }
    __syncthreads();

    const int w = t >> 6, lane = t & 63;
    const int lrow = lane & 15, lk = (lane >> 4) * 8, rgrp = (lane >> 4) * 4;
    floatx4 acc[4] = {};
    const unsigned short* ax = &xs[(w * 16 + lrow) * LDT + lk];
    for (int kt = 0; kt < 8; ++kt) {
        short8 a = *(const short8*)(ax + kt * 32);
        #pragma unroll
        for (int j = 0; j < 4; ++j) {
            short8 b = *(const short8*)&ws[(j * 16 + lrow) * LDT + kt * 32 + lk];
            acc[j] = __builtin_amdgcn_mfma_f32_16x16x32_bf16(a, b, acc[j], 0, 0, 0);
        }
    }

    if (vt_out) {
        __syncthreads();
        unsigned short* ts = xs;
        #pragma unroll
        for (int j = 0; j < 4; ++j) {
            float bv = __bfloat162float(bias[n0 + j * 16 + lrow]);
            #pragma unroll
            for (int r = 0; r < 4; ++r)
                ts[(j * 16 + lrow) * 72 + w * 16 + rgrp + r] = f2bfbits(acc[j][r] + bv);
        }
        __syncthreads();
        const int bq = m0 >> 11, s0v = m0 & 2047, h = n0 >> 6;
        bf16* dstb = (bf16*)Yv + ((size_t)(bq * HH + h) * HD) * SS + s0v;
        for (int i = 0; i < 2; ++i) {
            int idx = t + i * 256, row = idx >> 3, ch = (idx & 7) * 8;
            *(uint4*)(dstb + (size_t)row * SS + ch) = *(const uint4*)&ts[row * 72 + ch];
        }
        return;
    }

    const bool f32o = flex_out && (*flagp != 0);
    #pragma unroll
    for (int j = 0; j < 4; ++j) {
        int col = n0 + j * 16 + lrow;
        float bv = __bfloat162float(bias[col]);
        #pragma unroll
        for (int r = 0; r < 4; ++r) {
            int row = m0 + w * 16 + rgrp + r;
            float val = acc[j][r] + bv;
            if (f32o) ((float*)Yv)[(size_t)row * DD + col] = val;
            else      ((bf16*)Yv)[(size_t)row * DD + col] = __float2bfloat16(val);
        }
    }
}

// ---------------------------------------------------------------------------
// Class-dependent key v3.
// 256 thr / 4 waves; block = 128 rows x 64 cols; each wave computes TWO
// 16-row m-tiles -> every B-fragment ds_read_b128 feeds 2 MFMAs, halving
// LDS B-read traffic (the measured bottleneck at R5). X in registers
// (xa[2][8]), Wk ping-pong staged via global_load_lds + XOR chunk swizzle.
// ---------------------------------------------------------------------------
__device__ inline void stage_ws4(const bf16* __restrict__ Wc,
                                 unsigned short* wsbuf, int w, int lane)
{
    #pragma unroll
    for (int i = 0; i < 8; ++i) {
        int rr = w * 16 + i * 2 + (lane >> 5);       // row 0..63 of the slice
        int cs = (lane & 31) ^ (rr & 7);             // swizzled global chunk
        const bf16* src = Wc + (size_t)rr * DD + cs * 8;
        unsigned short* dst = wsbuf + (size_t)(w * 16 + i * 2) * DD;  // wave-uniform
#if HAVE_GLL
        __builtin_amdgcn_global_load_lds(
            (const __attribute__((address_space(1))) void*)src,
            (__attribute__((address_space(3))) void*)dst, 16, 0, 0);
#else
        uint4 v = *(const uint4*)src;
        *(uint4*)(dst + (size_t)lane * 8) = v;
#endif
    }
}

__launch_bounds__(256, 2)
__global__ void classkey(const bf16* __restrict__ X, const bf16* __restrict__ Cond,
                         const bf16* __restrict__ Wk, const bf16* __restrict__ Wkb,
                         bf16* __restrict__ Kout)
{
    __shared__ __align__(16) unsigned short ws[2][64 * 256];   // 64 KB ping-pong
    __shared__ __align__(16) unsigned short conds[128 * 32];   // 8 KB
    __shared__ __align__(16) unsigned short kbs[32 * 64];      // 4 KB
    const int t    = threadIdx.x;
    const int w    = t >> 6;            // wave 0..3
    const int lane = t & 63;
    const int r16  = lane & 15;
    const int quad = lane >> 4;
    const int m0   = blockIdx.y * 128;
    const int n0   = blockIdx.x * 64;

    // cond tile 128x32: 512 uint4 chunks, 2 per thread
    #pragma unroll
    for (int i = 0; i < 2; ++i) {
        int chunk = t + i * 256;
        int row = chunk >> 2, c8 = (chunk & 3) * 8;
        *(uint4*)&conds[row * 32 + c8] = *(const uint4*)(Cond + (size_t)(m0 + row) * CC + c8);
    }
    // Wk_b slice 32x64
    {
        int row = t >> 3, c8 = (t & 7) * 8;
        *(uint4*)&kbs[row * 64 + c8] = *(const uint4*)(Wkb + (size_t)row * DD + n0 + c8);
    }

    // X rows for this wave's two m-tiles -> registers
    short8 xa[2][8];
    #pragma unroll
    for (int mt = 0; mt < 2; ++mt) {
        const bf16* xrow = X + (size_t)(m0 + w * 32 + mt * 16 + r16) * DD + quad * 8;
        #pragma unroll
        for (int kt = 0; kt < 8; ++kt)
            xa[mt][kt] = *(const short8*)(xrow + kt * 32);
    }

    stage_ws4(Wk + (size_t)n0 * DD, &ws[0][0], w, lane);

    floatx4 acck[2][4] = {};
    for (int c = 0; c < CC; ++c) {
        __syncthreads();   // vmcnt(0) drain: buf[c&1] staged; buf[(c+1)&1] free
        if (c + 1 < CC)
            stage_ws4(Wk + (size_t)(c + 1) * DD * DD + (size_t)n0 * DD,
                      &ws[(c + 1) & 1][0], w, lane);

        const unsigned short* wb = &ws[c & 1][0];
        floatx4 p[2][4] = {};
        #pragma unroll
        for (int kt = 0; kt < 8; ++kt) {
            short8 bj[4];
            #pragma unroll
            for (int j = 0; j < 4; ++j)
                bj[j] = *(const short8*)&wb[(j * 16 + r16) * DD +
                                            (((kt * 4 + quad) ^ (r16 & 7)) << 3)];
            #pragma unroll
            for (int mt = 0; mt < 2; ++mt)
                #pragma unroll
                for (int j = 0; j < 4; ++j)
                    p[mt][j] = __builtin_amdgcn_mfma_f32_16x16x32_bf16(xa[mt][kt], bj[j], p[mt][j], 0, 0, 0);
        }
        #pragma unroll
        for (int mt = 0; mt < 2; ++mt)
            #pragma unroll
            for (int r = 0; r < 4; ++r) {
                float cv = bf2f(conds[(w * 32 + mt * 16 + quad * 4 + r) * 32 + c]);
                #pragma unroll
                for (int j = 0; j < 4; ++j) acck[mt][j][r] += cv * p[mt][j][r];
            }
    }

    // bias: sum_c cond[row,c] * Wkb[c,col]
    float kbv[2][4][4] = {};
    for (int c = 0; c < CC; ++c) {
        #pragma unroll
        for (int mt = 0; mt < 2; ++mt)
            #pragma unroll
            for (int r = 0; r < 4; ++r) {
                float cf = bf2f(conds[(w * 32 + mt * 16 + quad * 4 + r) * 32 + c]);
                #pragma unroll
                for (int j = 0; j < 4; ++j)
                    kbv[mt][j][r] += cf * bf2f(kbs[c * 64 + j * 16 + r16]);
            }
    }
    #pragma unroll
    for (int mt = 0; mt < 2; ++mt)
        #pragma unroll
        for (int j = 0; j < 4; ++j) {
            int col = n0 + j * 16 + r16;
            #pragma unroll
            for (int r = 0; r < 4; ++r) {
                int row = m0 + w * 32 + mt * 16 + quad * 4 + r;
                Kout[(size_t)row * DD + col] = __float2bfloat16(acck[mt][j][r] + kbv[mt][j][r]);
            }
        }
}

// ---------------------------------------------------------------------------
// Flash attention v2 (unchanged from R5 — validated).
// ---------------------------------------------------------------------------
__device__ inline void stage_kv(const bf16* __restrict__ kRow,
                                const bf16* __restrict__ vRow,
                                unsigned short* kbuf, unsigned short* vbuf,
                                int w, int lane)
{
    int r  = w * 8 + (lane >> 3);
    int cs = (lane & 7) ^ (r & 7);
#if HAVE_GLL
    __builtin_amdgcn_global_load_lds(
        (const __attribute__((address_space(1))) void*)(kRow + (size_t)r * DD + cs * 8),
        (__attribute__((address_space(3))) void*)(kbuf + w * 512), 16, 0, 0);
    __builtin_amdgcn_global_load_lds(
        (const __attribute__((address_space(1))) void*)(vRow + (size_t)r * SS + cs * 8),
        (__attribute__((address_space(3))) void*)(vbuf + w * 512), 16, 0, 0);
#else
    *(uint4*)(kbuf + w * 512 + (size_t)lane * 8) = *(const uint4*)(kRow + (size_t)r * DD + cs * 8);
    *(uint4*)(vbuf + w * 512 + (size_t)lane * 8) = *(const uint4*)(vRow + (size_t)r * SS + cs * 8);
#endif
}

__launch_bounds__(512, 4)
__global__ void attn(const bf16* __restrict__ Q, const bf16* __restrict__ Kb,
                     const bf16* __restrict__ VT, bf16* __restrict__ O)
{
    __shared__ __align__(16) unsigned short ks[2][64 * 64];
    __shared__ __align__(16) unsigned short vt[2][64 * 64];
#if !HAVE_PV16
    __shared__ __align__(16) unsigned short ps[128 * 72];
#endif
    const int t    = threadIdx.x;
    const int w    = t >> 6;
    const int lane = t & 63;
    const int r16  = lane & 15;
    const int quad = lane >> 4;
    const int bh   = blockIdx.y;
    const int b    = bh >> 2, h = bh & 3;
    const int q0   = blockIdx.x * 128;
    const size_t base  = ((size_t)b * SS) * DD + h * HD;
    const size_t vbase = (size_t)bh * HD * SS;

    short8 qa[2];
    {
        const bf16* qrow = Q + base + (size_t)(q0 + w * 16 + r16) * DD + quad * 8;
        #pragma unroll
        for (int k2 = 0; k2 < 2; ++k2) {
            short8 raw = *(const short8*)(qrow + k2 * 32);
            short8 sc;
            #pragma unroll
            for (int e = 0; e < 8; ++e)
                sc[e] = (short)f2bfbits(bf2f((unsigned short)raw[e]) * 0.125f);
            qa[k2] = sc;
        }
    }

    stage_kv(Kb + base, VT + vbase, &ks[0][0], &vt[0][0], w, lane);

    floatx4 acco[4] = {};
    float mrun = -1e30f, lrun = 0.f;

    for (int kt = 0; kt < SS / 64; ++kt) {
        __syncthreads();
        if (kt + 1 < SS / 64)
            stage_kv(Kb + base + (size_t)(kt + 1) * 64 * DD,
                     VT + vbase + (size_t)(kt + 1) * 64,
                     &ks[(kt + 1) & 1][0], &vt[(kt + 1) & 1][0], w, lane);

        const unsigned short* kbuf = &ks[kt & 1][0];
        const unsigned short* vbuf = &vt[kt & 1][0];

        floatx4 s[4] = {};
        #pragma unroll
        for (int k2 = 0; k2 < 2; ++k2) {
            short8 bq = qa[k2];
            #pragma unroll
            for (int j = 0; j < 4; ++j) {
                short8 ak = *(const short8*)&kbuf[(j * 16 + r16) * 64 +
                                                  (((k2 * 4 + quad) ^ (r16 & 7)) << 3)];
                s[j] = __builtin_amdgcn_mfma_f32_16x16x32_bf16(ak, bq, s[j], 0, 0, 0);
            }
        }

        float mx = -1e30f;
        #pragma unroll
        for (int j = 0; j < 4; ++j)
            #pragma unroll
            for (int r = 0; r < 4; ++r) mx = fmaxf(mx, s[j][r]);
        mx = fmaxf(mx, __shfl_xor(mx, 16, 64));
        mx = fmaxf(mx, __shfl_xor(mx, 32, 64));
        float mnew  = fmaxf(mrun, mx);
        float alpha = __expf(mrun - mnew);
        float sum = 0.f;
        #pragma unroll
        for (int j = 0; j < 4; ++j)
            #pragma unroll
            for (int r = 0; r < 4; ++r) {
                float e = __expf(s[j][r] - mnew);
                s[j][r] = e; sum += e;
            }
        sum += __shfl_xor(sum, 16, 64);
        sum += __shfl_xor(sum, 32, 64);
        lrun = lrun * alpha + sum;
        mrun = mnew;

        #pragma unroll
        for (int r = 0; r < 4; ++r) {
            float ar = __shfl(alpha, (quad << 4) + quad * 4 + r, 64);
            #pragma unroll
            for (int jn = 0; jn < 4; ++jn) acco[jn][r] *= ar;
        }

#if HAVE_PV16
        #pragma unroll
        for (int j = 0; j < 4; ++j) {
            short4v p;
            p[0] = (short)f2bfbits(s[j][0]); p[1] = (short)f2bfbits(s[j][1]);
            p[2] = (short)f2bfbits(s[j][2]); p[3] = (short)f2bfbits(s[j][3]);
            #pragma unroll
            for (int jn = 0; jn < 4; ++jn) {
                short4v vv = *(const short4v*)&vbuf[(jn * 16 + r16) * 64 +
                                                    ((((j * 2) + (quad >> 1)) ^ (r16 & 7)) << 3) +
                                                    (quad & 1) * 4];
                acco[jn] = MFMA_PV16(p, vv, acco[jn]);
            }
        }
#else
        #pragma unroll
        for (int j = 0; j < 4; ++j)
            #pragma unroll
            for (int r = 0; r < 4; ++r)
                ps[(w * 16 + r16) * 72 + j * 16 + quad * 4 + r] = f2bfbits(s[j][r]);
        #pragma unroll
        for (int k2 = 0; k2 < 2; ++k2) {
            short8 a = *(const short8*)&ps[(w * 16 + r16) * 72 + k2 * 32 + quad * 8];
            #pragma unroll
            for (int jn = 0; jn < 4; ++jn) {
                short8 bb = *(const short8*)&vbuf[(jn * 16 + r16) * 64 +
                                                  (((k2 * 4 + quad) ^ (r16 & 7)) << 3)];
                acco[jn] = __builtin_amdgcn_mfma_f32_16x16x32_bf16(a, bb, acco[jn], 0, 0, 0);
            }
        }
#endif
    }

    #pragma unroll
    for (int r = 0; r < 4; ++r) {
        float lr = __shfl(lrun, (quad << 4) + quad * 4 + r, 64);
        float inv = 1.0f / lr;
        int row = q0 + w * 16 + quad * 4 + r;
        #pragma unroll
        for (int jn = 0; jn < 4; ++jn)
            O[base + (size_t)row * DD + jn * 16 + r16] = __float2bfloat16(acco[jn][r] * inv);
    }
}

// ---------------------------------------------------------------------------
extern "C" void kernel_launch(void* const* d_in, const int* in_sizes, int n_in,
                              void* d_out, int out_size, void* d_ws, size_t ws_size,
                              hipStream_t stream)
{
    int*  flag = (int*)d_ws;
    bf16* conv = (bf16*)((char*)d_ws + 256);

    const bf16* xb    = conv + P0;
    const bf16* condb = conv + P1;
    const bf16* wqw   = conv + P2;
    const bf16* wqb   = conv + P3;
    const bf16* wvw   = conv + P4;
    const bf16* wvb   = conv + P5;
    const bf16* wkw   = conv + P6;
    const bf16* wkb   = conv + P7;
    const bf16* wow   = conv + P8;
    const bf16* wob   = conv + P9;

    bf16* qb = conv + PTOT;
    bf16* kb = qb + (size_t)MTOT * DD;
    bf16* vb = kb + (size_t)MTOT * DD;   // V^T layout [b*H+h][hd][S]
    bf16* ob = vb + (size_t)MTOT * DD;

    dim3 blk(256);
    hipLaunchKernelGGL(detect_dtype, dim3(1), blk, 0, stream, d_in[0], flag);
    hipLaunchKernelGGL(convert_all, dim3((PTOT / 8 + 255) / 256), blk, 0, stream,
                       d_in[0], d_in[1], d_in[2], d_in[3], d_in[4],
                       d_in[5], d_in[6], d_in[7], d_in[8], d_in[9],
                       conv, flag);

    dim3 gg(DD / 64, MTOT / 64);
    hipLaunchKernelGGL(gemm_bias, gg, blk, 0, stream, xb, wqw, wqb, (void*)qb, flag, 0, 0);
    hipLaunchKernelGGL(gemm_bias, gg, blk, 0, stream, xb, wvw, wvb, (void*)vb, flag, 0, 1);
    dim3 gck(DD / 64, MTOT / 128);       // (4, 128), 256-thread blocks
    hipLaunchKernelGGL(classkey, gck, dim3(256), 0, stream, xb, condb, wkw, wkb, kb);
    dim3 ga(SS / 128, BB * HH);          // (16, 32), 512-thread blocks
    hipLaunchKernelGGL(attn, ga, dim3(512), 0, stream, qb, kb, vb, ob);
    hipLaunchKernelGGL(gemm_bias, gg, blk, 0, stream, ob, wow, wob, d_out, flag, 1, 0);
}